// Round 11
// baseline (1699.296 us; speedup 1.0000x reference)
//
#include <hip/hip_runtime.h>
#include <cstdio>

#define NODES 153600
#define PJ 150
#define NJETS 1024
#define DEG 16
#define NEDGE (NODES*DEG)
#define HD 256
#define NCL 10

#define LSTR 168   // padded stride (u16) for Ls/Tt rows: 84 dw ≡ 20 mod 32 -> ~2-way
#define TSTR 88    // padded stride (u16) for Tn rows: 176B (16B-aligned), 44 dw ≡ 12 mod 32 -> spread

typedef unsigned short u16;  // fp16 bit pattern
typedef _Float16 f16;
typedef f16 f16x8 __attribute__((ext_vector_type(8)));
typedef u16 u16x8 __attribute__((ext_vector_type(8)));
typedef u16 u16x4 __attribute__((ext_vector_type(4)));
typedef float f32x4 __attribute__((ext_vector_type(4)));

__device__ inline float h2f(u16 u) { union { u16 s; f16 h; } v; v.s = u; return (float)v.h; }
__device__ inline u16 f2h(float f) { union { u16 s; f16 h; } v; v.h = (f16)f; return v.s; }

// ---------------- diagnostic ----------------
__global__ void k_diag(float* out, float code) {
  if (blockIdx.x == 0 && threadIdx.x == 0) out[0] = code;
}

// ---------------- graph preprocessing ----------------

__global__ __launch_bounds__(256) void k_dis(const int* __restrict__ tgt, float* __restrict__ dis) {
  int n = blockIdx.x*256 + threadIdx.x;
  if (n >= NODES) return;
  int cnt = 0;
#pragma unroll
  for (int j = 0; j < DEG; ++j) cnt += (tgt[n*DEG + j] != n) ? 1 : 0;
  dis[n] = (cnt > 0) ? rsqrtf((float)cnt) : 0.f;
}

__global__ __launch_bounds__(256) void k_counts(const int* __restrict__ tgt, int* __restrict__ counts) {
  int e = blockIdx.x*256 + threadIdx.x;
  if (e >= NEDGE) return;
  atomicAdd(&counts[tgt[e]], 1);
}

__global__ __launch_bounds__(256) void k_scan(const int* __restrict__ counts, int* __restrict__ rowptr, int* __restrict__ cursor) {
  int j = blockIdx.x*256 + threadIdx.x;
  if (j >= NJETS) return;
  int run = j*PJ*DEG;
  for (int l = 0; l < PJ; ++l) {
    int idx = j*PJ + l;
    int cnt = counts[idx];
    rowptr[idx] = run;
    cursor[idx] = run;
    run += cnt;
  }
  if (j == 0) rowptr[NODES] = NEDGE;
}

__global__ __launch_bounds__(256) void k_fill(const int* __restrict__ src_, const int* __restrict__ tgt_,
                                              const float* __restrict__ dis, int* __restrict__ cursor,
                                              unsigned char* __restrict__ ccol, float* __restrict__ cw) {
  int e = blockIdx.x*256 + threadIdx.x;
  if (e >= NEDGE) return;
  int s = src_[e], t = tgt_[e];
  int pos = atomicAdd(&cursor[t], 1);
  ccol[pos] = (unsigned char)(s % PJ);
  cw[pos] = (s != t) ? -(dis[s]*dis[t]) : 0.f;
}

// ---------------- dense per-jet 2*Laplacian: Lg[jet][160][160] f16 ----------------
__global__ __launch_bounds__(256) void k_prepL(const int* __restrict__ rowptr,
                                               const unsigned char* __restrict__ ccol,
                                               const float* __restrict__ cw,
                                               u16* __restrict__ Lg) {
  int j = blockIdx.x, tid = threadIdx.x;
  u16* L = Lg + (size_t)j*160*160;
  if (tid < 160) {
    u16x8 z = {0,0,0,0,0,0,0,0};
    for (int seg = 0; seg < 20; ++seg) *(u16x8*)&L[tid*160 + seg*8] = z;
    if (tid < PJ) {
      int es = rowptr[j*PJ + tid], ee = rowptr[j*PJ + tid + 1];
      u16* row = L + tid*160;
      for (int e = es; e < ee; ++e) {
        int c = (int)ccol[e];
        row[c] = f2h(h2f(row[c]) + 2.f*cw[e]);   // L2 = 2*Lhat
      }
    }
  }
}

// ---------------- layer 1: fused 5 sparse props (din=3), writes Tall[N][18] fp32 ----------------
__global__ __launch_bounds__(512) void k_cheb3(const float* __restrict__ x,
                                               const int* __restrict__ rowptr,
                                               const unsigned char* __restrict__ ccol,
                                               const float* __restrict__ cw,
                                               float* __restrict__ tall) {
  __shared__ float Ta[450], Tb[450];
  __shared__ float cw_s[PJ*DEG];
  __shared__ u16  col_s[PJ*DEG];
  __shared__ int  rp_s[PJ+1];
  int j = blockIdx.x, tid = threadIdx.x;
  int jb = j*PJ, e0 = jb*DEG;
  for (int i = tid; i < PJ*DEG; i += 512) { cw_s[i] = cw[e0+i]; col_s[i] = (u16)ccol[e0+i]; }
  for (int i = tid; i < PJ+1; i += 512) rp_s[i] = rowptr[jb+i] - e0;
  if (tid < 450) Ta[tid] = x[(size_t)jb*3 + tid];
  __syncthreads();
  int r = tid/3, c = tid - r*3;
  float* cur = Ta; float* oth = Tb;
  if (tid < 450) tall[(size_t)(jb+r)*18 + c] = cur[tid];
  for (int t = 1; t < 6; ++t) {
    if (tid < 450) {
      int es = rp_s[r], ee = rp_s[r+1];
      float acc = 0.f;
      for (int e = es; e < ee; ++e) acc += cw_s[e]*cur[(int)col_s[e]*3 + c];
      float v = (t == 1) ? acc : 2.f*acc - oth[tid];
      oth[tid] = v;
      tall[(size_t)(jb+r)*18 + t*3 + c] = v;
    }
    __syncthreads();
    float* tmp = cur; cur = oth; oth = tmp;
  }
}

// out[n,c] = sum_{i<18} Tall[n,i] * W1[i,c]; fused BN stats (with bias b1)
__global__ __launch_bounds__(256) void k_gemm1(const float* __restrict__ tall, const float* __restrict__ W1,
                                               const float* __restrict__ b1, float* __restrict__ stats,
                                               u16* __restrict__ outc) {
  __shared__ float wl[18*256];
  __shared__ float tl[64*18];
  int c = threadIdx.x;
  for (int i = c; i < 18*256; i += 256) wl[i] = W1[i];
  int n0 = blockIdx.x*64;
  __syncthreads();
  for (int i = c; i < 64*18; i += 256) tl[i] = tall[(size_t)n0*18 + i];
  __syncthreads();
  float bc = b1[c];
  float s = 0.f, s2 = 0.f;
  for (int n = 0; n < 64; ++n) {
    float acc = 0.f;
#pragma unroll
    for (int i = 0; i < 18; ++i) acc += tl[n*18 + i] * wl[i*256 + c];
    outc[(size_t)(n0+n)*HD + c] = f2h(acc);
    float vb = acc + bc;
    s += vb; s2 += vb*vb;
  }
  atomicAdd(&stats[c], s);
  atomicAdd(&stats[HD + c], s2);
}

// ---------------- W prep (merged): WT[layer][cout][k] f16, k = term*256 + cin ----------------
__global__ __launch_bounds__(256) void k_prepW3(const float* __restrict__ Wa, const float* __restrict__ Wb,
                                                const float* __restrict__ Wc, u16* __restrict__ WT) {
  int i = blockIdx.x*256 + threadIdx.x;
  if (i >= 3*256*1536) return;
  int layer = i / (256*1536);
  int rem = i - layer*(256*1536);
  int cout = rem / 1536, k = rem - cout*1536;
  int term = k >> 8, cin = k & 255;
  const float* W = (layer == 0) ? Wa : (layer == 1) ? Wb : Wc;
  WT[i] = f2h(W[(size_t)term*65536 + cin*256 + cout]);
}

// ---------------- fused per-jet Chebyshev layer ----------------
// Input = raw OUT of previous layer; BN(affine from statsPrev/gP/beP/bP)+LeakyReLU applied
// during T0 staging. Epilogue: OMODE 0 -> BN stats (bias bCur) for the NEXT layer;
// OMODE 1 -> per-row sum((v+bCur)^2) into rn[] for the rownorm+pool.
// Ls ks∈{0,1} A-fragments register-cached (invariant across terms/quarters).
template<int OMODE>
__global__ __launch_bounds__(1024, 4) void k_cheb(const u16* __restrict__ IN,
                                                  const u16* __restrict__ WTu,
                                                  const u16* __restrict__ Lg,
                                                  const float* __restrict__ statsPrev,
                                                  const float* __restrict__ gP,
                                                  const float* __restrict__ beP,
                                                  const float* __restrict__ bP,
                                                  const float* __restrict__ bCur,
                                                  float* __restrict__ statsCur,
                                                  float* __restrict__ rn,
                                                  u16* __restrict__ OUTp) {
  __shared__ u16 Ls[160*LSTR];
  __shared__ u16 Tn[2][160*TSTR];
  __shared__ u16 Tt[2][64*LSTR];
  __shared__ float bnA[HD], bnB[HD];
  int j = blockIdx.x, tid = threadIdx.x;
  int jb = j*PJ;
  int lane = tid & 63, wid = tid >> 6;
  int wm = wid >> 3, wn = wid & 7;          // 2(M) x 8(N)
  int lr = lane & 15, lg = lane >> 4;
  int ph = wn >> 2, cs = wn & 3;            // prop: half + 16-ch slice
  int cown = cs*16 + lr;
  const f16* WT = (const f16*)WTu;

  // BN tables: staged value = lrelu(IN*A + B)
  if (tid < HD) {
    const float invN = 1.f/(float)NODES;
    float m = statsPrev[tid]*invN;
    float var = statsPrev[HD+tid]*invN - m*m;
    float A = rsqrtf(var + 1e-5f) * gP[tid];
    bnA[tid] = A;
    bnB[tid] = (bP[tid] - m)*A + beP[tid];
  }
  // stage dense L once
  {
    const u16* src = Lg + (size_t)j*25600;
    for (int i = tid; i < 3200; i += 1024) {
      int row = i/20, seg = i - row*20;
      *(u16x8*)&Ls[row*LSTR + seg*8] = *(const u16x8*)&src[row*160 + seg*8];
    }
  }
  __syncthreads();
  // register-cache Ls A-fragments for ks 0..1 (invariant across terms/quarters)
  f16x8 lreg[2][5];
#pragma unroll
  for (int ks = 0; ks < 2; ++ks)
#pragma unroll
    for (int mf = 0; mf < 5; ++mf)
      lreg[ks][mf] = *(const f16x8*)&Ls[(wm*80 + mf*16 + lr)*LSTR + ks*32 + lg*8];

  f32x4 acc[5][2];
#pragma unroll
  for (int a = 0; a < 5; ++a)
#pragma unroll
    for (int b = 0; b < 2; ++b) acc[a][b] = (f32x4)0.f;

  for (int qp = 0; qp < 2; ++qp) {
    __syncthreads();   // prior-pair reads done
    // stage T0 = lrelu(BN(IN)) for quarters (qp*2, qp*2+1); zero rows 150..159
    for (int i = tid; i < 2560; i += 1024) {
      int h = (i >= 1280) ? 1 : 0;
      int rem = i - h*1280;
      int row = rem >> 3, seg = rem & 7;
      u16x8 o = {0,0,0,0,0,0,0,0};
      if (row < PJ) {
        int c0 = (qp*2+h)*64 + seg*8;
        u16x8 v = *(const u16x8*)&IN[(size_t)(jb+row)*HD + c0];
#pragma unroll
        for (int u = 0; u < 8; ++u) {
          float f = h2f(v[u])*bnA[c0+u] + bnB[c0+u];
          o[u] = f2h((f > 0.f) ? f : 0.01f*f);
        }
      }
      *(u16x8*)&Tn[h][row*TSTR + seg*8] = o;
    }
    __syncthreads();
    // build Ttr (bank-spread mapping)
    for (int i = tid; i < 2560; i += 1024) {
      int h = (i >= 1280) ? 1 : 0;
      int rem = i - h*1280;
      int c = rem & 63, m = rem >> 6;
      u16x8 v;
#pragma unroll
      for (int u = 0; u < 8; ++u) v[u] = Tn[h][(m*8+u)*TSTR + c];
      *(u16x8*)&Tt[h][c*LSTR + m*8] = v;
    }
    // own-slot T0 registers (this wave's half only)
    u16x4 tcur[5], tprev[5];
#pragma unroll
    for (int mf = 0; mf < 5; ++mf) {
      int r0 = wm*80 + mf*16 + lg*4;
#pragma unroll
      for (int e = 0; e < 4; ++e) tcur[mf][e] = Tn[ph][(r0+e)*TSTR + cown];
      tprev[mf] = tcur[mf];
    }
    __syncthreads();
#pragma unroll 1
    for (int t = 0; t < 6; ++t) {
      // ---- weight GEMM, both halves: acc += T_t @ W_t (wave tile 80x32) ----
#pragma unroll
      for (int h = 0; h < 2; ++h) {
        int kbase = t*256 + (qp*2+h)*64;
#pragma unroll
        for (int ks = 0; ks < 64; ks += 32) {
          f16x8 a[5], bv[2];
#pragma unroll
          for (int nf = 0; nf < 2; ++nf)
            bv[nf] = *(const f16x8*)&WT[(size_t)(wn*32 + nf*16 + lr)*1536 + kbase + ks + lg*8];
#pragma unroll
          for (int mf = 0; mf < 5; ++mf)
            a[mf] = *(const f16x8*)&Tn[h][(wm*80 + mf*16 + lr)*TSTR + ks + lg*8];
#pragma unroll
          for (int nf = 0; nf < 2; ++nf)
#pragma unroll
            for (int mf = 0; mf < 5; ++mf)
              acc[mf][nf] = __builtin_amdgcn_mfma_f32_16x16x32_f16(a[mf], bv[nf], acc[mf][nf], 0, 0, 0);
        }
      }
      if (t < 5) {
        // ---- prop MFMA: pacc = L2 @ T_t for this wave's (half, 16-ch slice) ----
        f32x4 pacc[5];
#pragma unroll
        for (int mf = 0; mf < 5; ++mf) pacc[mf] = (f32x4)0.f;
#pragma unroll
        for (int ks = 0; ks < 5; ++ks) {
          f16x8 b = *(const f16x8*)&Tt[ph][cown*LSTR + ks*32 + lg*8];
#pragma unroll
          for (int mf = 0; mf < 5; ++mf) {
            f16x8 a = (ks < 2) ? lreg[ks][mf]
                               : *(const f16x8*)&Ls[(wm*80 + mf*16 + lr)*LSTR + ks*32 + lg*8];
            pacc[mf] = __builtin_amdgcn_mfma_f32_16x16x32_f16(a, b, pacc[mf], 0, 0, 0);
          }
        }
        __syncthreads();   // all Tn/Tt reads of term t complete
        // epilogue: T_{t+1} = pacc - T_{t-1} (0.5*pacc at t=0); owner-exclusive slots
#pragma unroll
        for (int mf = 0; mf < 5; ++mf) {
          int r0 = wm*80 + mf*16 + lg*4;
          u16x4 o;
#pragma unroll
          for (int e = 0; e < 4; ++e) {
            float v = (t == 0) ? 0.5f*pacc[mf][e]
                               : pacc[mf][e] - h2f(tprev[mf][e]);
            o[e] = f2h(v);
            Tn[ph][(r0+e)*TSTR + cown] = o[e];
          }
          *(u16x4*)&Tt[ph][cown*LSTR + r0] = o;
          tprev[mf] = tcur[mf];
          tcur[mf] = o;
        }
        __syncthreads();
      }
    }
  }
  // ---- OUT epilogue + fused stats / rowsumsq ----
  if (OMODE == 0) {
#pragma unroll
    for (int nf = 0; nf < 2; ++nf) {
      int col = wn*32 + nf*16 + lr;
      float bc = bCur[col];
      float s = 0.f, s2 = 0.f;
#pragma unroll
      for (int mf = 0; mf < 5; ++mf) {
        int row = wm*80 + mf*16 + lg*4;
#pragma unroll
        for (int e = 0; e < 4; ++e) {
          int r = row + e;
          if (r < PJ) {
            float v = acc[mf][nf][e];
            OUTp[(size_t)(jb+r)*HD + col] = f2h(v);
            float vb = v + bc;
            s += vb; s2 += vb*vb;
          }
        }
      }
      s  += __shfl_xor(s, 16, 64);  s  += __shfl_xor(s, 32, 64);
      s2 += __shfl_xor(s2, 16, 64); s2 += __shfl_xor(s2, 32, 64);
      if (lg == 0) {
        atomicAdd(&statsCur[col], s);
        atomicAdd(&statsCur[HD + col], s2);
      }
    }
  } else {
    float bc[2];
#pragma unroll
    for (int nf = 0; nf < 2; ++nf) bc[nf] = bCur[wn*32 + nf*16 + lr];
#pragma unroll
    for (int mf = 0; mf < 5; ++mf) {
      int row = wm*80 + mf*16 + lg*4;
#pragma unroll
      for (int e = 0; e < 4; ++e) {
        int r = row + e;
        float srow = 0.f;
        if (r < PJ) {
#pragma unroll
          for (int nf = 0; nf < 2; ++nf) {
            int col = wn*32 + nf*16 + lr;
            float v = acc[mf][nf][e];
            OUTp[(size_t)(jb+r)*HD + col] = f2h(v);
            float vb = v + bc[nf];
            srow += vb*vb;
          }
        }
        srow += __shfl_xor(srow, 1, 64);
        srow += __shfl_xor(srow, 2, 64);
        srow += __shfl_xor(srow, 4, 64);
        srow += __shfl_xor(srow, 8, 64);
        if (lr == 0 && r < PJ) atomicAdd(&rn[jb + r], srow);
      }
    }
  }
}

// ---------------- distance softmax pooling, fused row-normalize ----------------

__global__ __launch_bounds__(256) void k_pool(const u16* __restrict__ h, const float* __restrict__ rn,
                                              const float* __restrict__ bias, const float* __restrict__ x,
                                              const float* __restrict__ centers, const float* __restrict__ log_temp,
                                              float* __restrict__ out) {
  __shared__ float a_s[PJ][NCL];
  __shared__ float colsum[NCL];
  __shared__ float inv_s[PJ];
  int j = blockIdx.x;
  int tid = threadIdx.x;
  float T = expf(fminf(fmaxf(log_temp[0], -2.f), 3.f));
  if (tid < PJ) {
    int g = j*PJ + tid;
    inv_s[tid] = 1.f / fmaxf(sqrtf(rn[g]), 1e-12f);
    float eta = x[(size_t)g*3], phi = x[(size_t)g*3 + 1];
    float d[NCL];
    float dmin = 1e30f;
#pragma unroll
    for (int k = 0; k < NCL; ++k) {
      float dx = eta - centers[2*k], dy = phi - centers[2*k+1];
      d[k] = dx*dx + dy*dy;
      dmin = fminf(dmin, d[k]);
    }
    float s = 0.f, ek[NCL];
#pragma unroll
    for (int k = 0; k < NCL; ++k) { ek[k] = expf(-T*(d[k]-dmin)); s += ek[k]; }
    float invs = 1.f/s;
#pragma unroll
    for (int k = 0; k < NCL; ++k) a_s[tid][k] = ek[k]*invs;
  }
  __syncthreads();
  if (tid < NCL) {
    float s = 0.f;
    for (int n = 0; n < PJ; ++n) s += a_s[n][tid];
    colsum[tid] = s;
  }
  __syncthreads();
  int c = tid;
  float bc = bias[c];
  float acc[NCL] = {};
  for (int n = 0; n < PJ; ++n) {
    float hv = (h2f(h[(size_t)(j*PJ + n)*HD + c]) + bc) * inv_s[n];
#pragma unroll
    for (int k = 0; k < NCL; ++k) acc[k] += a_s[n][k]*hv;
  }
#pragma unroll
  for (int k = 0; k < NCL; ++k)
    out[(size_t)j*(NCL*HD) + k*HD + c] = acc[k] / (colsum[k] + 1e-8f);
}

// ---------------- host ----------------

extern "C" void kernel_launch(void* const* d_in, const int* in_sizes, int n_in,
                              void* d_out, int out_size, void* d_ws, size_t ws_size,
                              hipStream_t stream) {
  (void)in_sizes; (void)n_in; (void)out_size;
  const float* x   = (const float*)d_in[0];
  const int*   ei  = (const int*)d_in[1];
  const int*   srcA = ei;
  const int*   tgtA = ei + NEDGE;
  const float* W1  = (const float*)d_in[3];
  const float* b1  = (const float*)d_in[4];
  const float* W2  = (const float*)d_in[5];
  const float* b2  = (const float*)d_in[6];
  const float* W3  = (const float*)d_in[7];
  const float* b3  = (const float*)d_in[8];
  const float* W4  = (const float*)d_in[9];
  const float* b4  = (const float*)d_in[10];
  const float* g1  = (const float*)d_in[11];
  const float* be1 = (const float*)d_in[12];
  const float* g2  = (const float*)d_in[13];
  const float* be2 = (const float*)d_in[14];
  const float* g3  = (const float*)d_in[15];
  const float* be3 = (const float*)d_in[16];
  const float* centers  = (const float*)d_in[17];
  const float* log_temp = (const float*)d_in[18];
  float* out = (float*)d_out;

  auto rb = [](size_t b) { return (b + 255) & ~(size_t)255; };
  size_t need = 3*rb((size_t)NODES*HD*2)            // OUTA, OUTB, Y
              + 3*rb((size_t)NODES*4)               // dis, counts, cursor
              + rb((size_t)(NODES+1)*4)             // rowptr
              + rb((size_t)NEDGE)                   // ccol
              + rb((size_t)NEDGE*4)                 // cw
              + rb((size_t)3*2*HD*4)                // stats x3
              + rb((size_t)NODES*4);                // rn
  fprintf(stderr, "[kernel_launch] ws_size=%zu need=%zu\n", ws_size, need);
  if (d_ws == nullptr || ws_size < need) {
    float code = 1.0e6f + (float)(ws_size >> 20);
    k_diag<<<1, 1, 0, stream>>>(out, code);
    return;
  }

  char* wp = (char*)d_ws;
  auto alloc = [&](size_t b) -> void* {
    void* p = (void*)wp;
    wp += (b + 255) & ~(size_t)255;
    return p;
  };
  u16*   OUTA = (u16*)alloc((size_t)NODES*HD*2);
  u16*   OUTB = (u16*)alloc((size_t)NODES*HD*2);
  u16*   Y    = (u16*)alloc((size_t)NODES*HD*2);
  float* dis  = (float*)alloc((size_t)NODES*4);
  int*   counts = (int*)alloc((size_t)NODES*4);
  int*   cursor = (int*)alloc((size_t)NODES*4);
  int*   rowptr = (int*)alloc((size_t)(NODES+1)*4);
  unsigned char* ccol = (unsigned char*)alloc((size_t)NEDGE);
  float* cw     = (float*)alloc((size_t)NEDGE*4);
  float* stats  = (float*)alloc((size_t)3*2*HD*4);   // [3][512]
  float* rn     = (float*)alloc((size_t)NODES*4);
  // aliases into Y: layer-1 Tall (11 MB) first, then Lg (52.4 MB) + Wcat3 (2.4 MB)
  float* Tall = (float*)Y;
  u16*   Lg   = Y;
  u16*   Wcat = Y + (size_t)NJETS*160*160;
  float* s0 = stats, *s1 = stats + 512, *s2 = stats + 1024;

  // graph preprocessing
  hipMemsetAsync(counts, 0, (size_t)NODES*4, stream);
  k_dis<<<(NODES+255)/256, 256, 0, stream>>>(tgtA, dis);
  k_counts<<<(NEDGE+255)/256, 256, 0, stream>>>(tgtA, counts);
  k_scan<<<(NJETS+255)/256, 256, 0, stream>>>(counts, rowptr, cursor);
  k_fill<<<(NEDGE+255)/256, 256, 0, stream>>>(srcA, tgtA, dis, cursor, ccol, cw);

  // ---- layer 1 (din=3): fused props + small GEMM (+stats) ----
  k_cheb3<<<NJETS, 512, 0, stream>>>(x, rowptr, ccol, cw, Tall);
  hipMemsetAsync(s0, 0, (size_t)2*HD*4, stream);
  k_gemm1<<<NODES/64, 256, 0, stream>>>(Tall, W1, b1, s0, OUTA);

  // ---- dense Laplacian + all W conversions (after layer 1 frees the Y scratch) ----
  k_prepL<<<NJETS, 256, 0, stream>>>(rowptr, ccol, cw, Lg);
  k_prepW3<<<(3*256*1536+255)/256, 256, 0, stream>>>(W2, W3, W4, Wcat);

  // ---- layers 2..4: fused all-MFMA Cheb, BN-on-stage ----
  hipMemsetAsync(s1, 0, (size_t)2*HD*4, stream);
  k_cheb<0><<<NJETS, 1024, 0, stream>>>(OUTA, Wcat,            Lg, s0, g1, be1, b1, b2, s1, rn, OUTB);
  hipMemsetAsync(s2, 0, (size_t)2*HD*4, stream);
  k_cheb<0><<<NJETS, 1024, 0, stream>>>(OUTB, Wcat + 393216,   Lg, s1, g2, be2, b2, b3, s2, rn, OUTA);
  hipMemsetAsync(rn, 0, (size_t)NODES*4, stream);
  k_cheb<1><<<NJETS, 1024, 0, stream>>>(OUTA, Wcat + 2*393216, Lg, s2, g3, be3, b3, b4, s2, rn, OUTB);

  // ---- pooling (fused rownorm) ----
  k_pool<<<NJETS, 256, 0, stream>>>(OUTB, rn, b4, x, centers, log_temp, out);
}

// Round 12
// 1475.495 us; speedup vs baseline: 1.1517x; 1.1517x over previous
//
#include <hip/hip_runtime.h>
#include <cstdio>

#define NODES 153600
#define PJ 150
#define NJETS 1024
#define DEG 16
#define NEDGE (NODES*DEG)
#define HD 256
#define NCL 10

#define LSTR 192   // Ls/Tt row stride (u16): 96 dw ≡ 0 mod 32; conflicts killed by seg XOR-swizzle
#define TNS  64    // Tn row stride (u16): 32 dw ≡ 0 mod 32; seg XOR-swizzle

typedef unsigned short u16;  // fp16 bit pattern
typedef _Float16 f16;
typedef f16 f16x8 __attribute__((ext_vector_type(8)));
typedef u16 u16x8 __attribute__((ext_vector_type(8)));
typedef u16 u16x4 __attribute__((ext_vector_type(4)));
typedef float f32x4 __attribute__((ext_vector_type(4)));

__device__ inline float h2f(u16 u) { union { u16 s; f16 h; } v; v.s = u; return (float)v.h; }
__device__ inline u16 f2h(float f) { union { u16 s; f16 h; } v; v.h = (f16)f; return v.s; }
// XOR-swizzle a 16B segment index within its aligned 8-seg (128B) block
__device__ inline int swz(int seg, int key) { return (seg & ~7) | ((seg & 7) ^ (key & 7)); }

// ---------------- diagnostic ----------------
__global__ void k_diag(float* out, float code) {
  if (blockIdx.x == 0 && threadIdx.x == 0) out[0] = code;
}

// ---------------- graph preprocessing ----------------

__global__ __launch_bounds__(256) void k_dis(const int* __restrict__ tgt, float* __restrict__ dis) {
  int n = blockIdx.x*256 + threadIdx.x;
  if (n >= NODES) return;
  int cnt = 0;
#pragma unroll
  for (int j = 0; j < DEG; ++j) cnt += (tgt[n*DEG + j] != n) ? 1 : 0;
  dis[n] = (cnt > 0) ? rsqrtf((float)cnt) : 0.f;
}

__global__ __launch_bounds__(256) void k_counts(const int* __restrict__ tgt, int* __restrict__ counts) {
  int e = blockIdx.x*256 + threadIdx.x;
  if (e >= NEDGE) return;
  atomicAdd(&counts[tgt[e]], 1);
}

__global__ __launch_bounds__(256) void k_scan(const int* __restrict__ counts, int* __restrict__ rowptr, int* __restrict__ cursor) {
  int j = blockIdx.x*256 + threadIdx.x;
  if (j >= NJETS) return;
  int run = j*PJ*DEG;
  for (int l = 0; l < PJ; ++l) {
    int idx = j*PJ + l;
    int cnt = counts[idx];
    rowptr[idx] = run;
    cursor[idx] = run;
    run += cnt;
  }
  if (j == 0) rowptr[NODES] = NEDGE;
}

__global__ __launch_bounds__(256) void k_fill(const int* __restrict__ src_, const int* __restrict__ tgt_,
                                              const float* __restrict__ dis, int* __restrict__ cursor,
                                              unsigned char* __restrict__ ccol, float* __restrict__ cw) {
  int e = blockIdx.x*256 + threadIdx.x;
  if (e >= NEDGE) return;
  int s = src_[e], t = tgt_[e];
  int pos = atomicAdd(&cursor[t], 1);
  ccol[pos] = (unsigned char)(s % PJ);
  cw[pos] = (s != t) ? -(dis[s]*dis[t]) : 0.f;
}

// ---------------- dense per-jet 2*Laplacian: Lg[jet][160][160] f16 ----------------
__global__ __launch_bounds__(256) void k_prepL(const int* __restrict__ rowptr,
                                               const unsigned char* __restrict__ ccol,
                                               const float* __restrict__ cw,
                                               u16* __restrict__ Lg) {
  int j = blockIdx.x, tid = threadIdx.x;
  u16* L = Lg + (size_t)j*160*160;
  if (tid < 160) {
    u16x8 z = {0,0,0,0,0,0,0,0};
    for (int seg = 0; seg < 20; ++seg) *(u16x8*)&L[tid*160 + seg*8] = z;
    if (tid < PJ) {
      int es = rowptr[j*PJ + tid], ee = rowptr[j*PJ + tid + 1];
      u16* row = L + tid*160;
      for (int e = es; e < ee; ++e) {
        int c = (int)ccol[e];
        row[c] = f2h(h2f(row[c]) + 2.f*cw[e]);   // L2 = 2*Lhat
      }
    }
  }
}

// ---------------- layer 1: fused 5 sparse props (din=3), writes Tall[N][18] fp32 ----------------
__global__ __launch_bounds__(512) void k_cheb3(const float* __restrict__ x,
                                               const int* __restrict__ rowptr,
                                               const unsigned char* __restrict__ ccol,
                                               const float* __restrict__ cw,
                                               float* __restrict__ tall) {
  __shared__ float Ta[450], Tb[450];
  __shared__ float cw_s[PJ*DEG];
  __shared__ u16  col_s[PJ*DEG];
  __shared__ int  rp_s[PJ+1];
  int j = blockIdx.x, tid = threadIdx.x;
  int jb = j*PJ, e0 = jb*DEG;
  for (int i = tid; i < PJ*DEG; i += 512) { cw_s[i] = cw[e0+i]; col_s[i] = (u16)ccol[e0+i]; }
  for (int i = tid; i < PJ+1; i += 512) rp_s[i] = rowptr[jb+i] - e0;
  if (tid < 450) Ta[tid] = x[(size_t)jb*3 + tid];
  __syncthreads();
  int r = tid/3, c = tid - r*3;
  float* cur = Ta; float* oth = Tb;
  if (tid < 450) tall[(size_t)(jb+r)*18 + c] = cur[tid];
  for (int t = 1; t < 6; ++t) {
    if (tid < 450) {
      int es = rp_s[r], ee = rp_s[r+1];
      float acc = 0.f;
      for (int e = es; e < ee; ++e) acc += cw_s[e]*cur[(int)col_s[e]*3 + c];
      float v = (t == 1) ? acc : 2.f*acc - oth[tid];
      oth[tid] = v;
      tall[(size_t)(jb+r)*18 + t*3 + c] = v;
    }
    __syncthreads();
    float* tmp = cur; cur = oth; oth = tmp;
  }
}

// out[n,c] = sum_{i<18} Tall[n,i] * W1[i,c]; fused BN stats (with bias b1)
__global__ __launch_bounds__(256) void k_gemm1(const float* __restrict__ tall, const float* __restrict__ W1,
                                               const float* __restrict__ b1, float* __restrict__ stats,
                                               u16* __restrict__ outc) {
  __shared__ float wl[18*256];
  __shared__ float tl[64*18];
  int c = threadIdx.x;
  for (int i = c; i < 18*256; i += 256) wl[i] = W1[i];
  int n0 = blockIdx.x*64;
  __syncthreads();
  for (int i = c; i < 64*18; i += 256) tl[i] = tall[(size_t)n0*18 + i];
  __syncthreads();
  float bc = b1[c];
  float s = 0.f, s2 = 0.f;
  for (int n = 0; n < 64; ++n) {
    float acc = 0.f;
#pragma unroll
    for (int i = 0; i < 18; ++i) acc += tl[n*18 + i] * wl[i*256 + c];
    outc[(size_t)(n0+n)*HD + c] = f2h(acc);
    float vb = acc + bc;
    s += vb; s2 += vb*vb;
  }
  atomicAdd(&stats[c], s);
  atomicAdd(&stats[HD + c], s2);
}

// ---------------- W prep (merged): WT[layer][cout][k] f16, k = term*256 + cin ----------------
__global__ __launch_bounds__(256) void k_prepW3(const float* __restrict__ Wa, const float* __restrict__ Wb,
                                                const float* __restrict__ Wc, u16* __restrict__ WT) {
  int i = blockIdx.x*256 + threadIdx.x;
  if (i >= 3*256*1536) return;
  int layer = i / (256*1536);
  int rem = i - layer*(256*1536);
  int cout = rem / 1536, k = rem - cout*1536;
  int term = k >> 8, cin = k & 255;
  const float* W = (layer == 0) ? Wa : (layer == 1) ? Wb : Wc;
  WT[i] = f2h(W[(size_t)term*65536 + cin*256 + cout]);
}

// ---------------- fused per-jet Chebyshev layer ----------------
// Input = raw OUT of previous layer; BN(affine)+LeakyReLU applied during T0 staging.
// OMODE 0 -> BN stats for next layer; OMODE 1 -> per-row sumsq into rn[].
// All LDS tiles XOR-swizzled (unpadded strides ≡ 0 mod 32 dw; seg^(row&7) spreads banks).
template<int OMODE>
__global__ __launch_bounds__(1024, 4) void k_cheb(const u16* __restrict__ IN,
                                                  const u16* __restrict__ WTu,
                                                  const u16* __restrict__ Lg,
                                                  const float* __restrict__ statsPrev,
                                                  const float* __restrict__ gP,
                                                  const float* __restrict__ beP,
                                                  const float* __restrict__ bP,
                                                  const float* __restrict__ bCur,
                                                  float* __restrict__ statsCur,
                                                  float* __restrict__ rn,
                                                  u16* __restrict__ OUTp) {
  __shared__ u16 Ls[160*LSTR];         // 61.4 KB
  __shared__ u16 Tn[2][160*TNS];       // 41.0 KB
  __shared__ u16 Tt[2][64*LSTR];       // 49.2 KB
  __shared__ float bnA[HD], bnB[HD];   // 2 KB   -> 153.6 KB total
  int j = blockIdx.x, tid = threadIdx.x;
  int jb = j*PJ;
  int lane = tid & 63, wid = tid >> 6;
  int wm = wid >> 3, wn = wid & 7;          // 2(M) x 8(N)
  int lr = lane & 15, lg = lane >> 4;
  int ph = wn >> 2, cs = wn & 3;            // prop: half + 16-ch slice
  int cown = cs*16 + lr;
  const f16* WT = (const f16*)WTu;

  // BN tables: staged value = lrelu(IN*A + B)
  if (tid < HD) {
    const float invN = 1.f/(float)NODES;
    float m = statsPrev[tid]*invN;
    float var = statsPrev[HD+tid]*invN - m*m;
    float A = rsqrtf(var + 1e-5f) * gP[tid];
    bnA[tid] = A;
    bnB[tid] = (bP[tid] - m)*A + beP[tid];
  }
  // stage dense L once (swizzled)
  {
    const u16* src = Lg + (size_t)j*25600;
    for (int i = tid; i < 3200; i += 1024) {
      int row = i/20, seg = i - row*20;
      *(u16x8*)&Ls[row*LSTR + swz(seg,row)*8] = *(const u16x8*)&src[row*160 + seg*8];
    }
  }
  f32x4 acc[5][2];
#pragma unroll
  for (int a = 0; a < 5; ++a)
#pragma unroll
    for (int b = 0; b < 2; ++b) acc[a][b] = (f32x4)0.f;

  for (int qp = 0; qp < 2; ++qp) {
    __syncthreads();   // prior-pair reads done; bn/L staged at qp=0
    // stage T0 = lrelu(BN(IN)) for quarters (qp*2, qp*2+1); zero rows 150..159
    for (int i = tid; i < 2560; i += 1024) {
      int h = (i >= 1280) ? 1 : 0;
      int rem = i - h*1280;
      int row = rem >> 3, seg = rem & 7;
      u16x8 o = {0,0,0,0,0,0,0,0};
      if (row < PJ) {
        int c0 = (qp*2+h)*64 + seg*8;
        u16x8 v = *(const u16x8*)&IN[(size_t)(jb+row)*HD + c0];
#pragma unroll
        for (int u = 0; u < 8; ++u) {
          float f = h2f(v[u])*bnA[c0+u] + bnB[c0+u];
          o[u] = f2h((f > 0.f) ? f : 0.01f*f);
        }
      }
      *(u16x8*)&Tn[h][row*TNS + (seg ^ (row & 7))*8] = o;
    }
    __syncthreads();
    // build Ttr (swizzled both sides)
    for (int i = tid; i < 2560; i += 1024) {
      int h = (i >= 1280) ? 1 : 0;
      int rem = i - h*1280;
      int c = rem & 63, m = rem >> 6;
      u16x8 v;
#pragma unroll
      for (int u = 0; u < 8; ++u) {
        int r = m*8 + u;
        v[u] = Tn[h][r*TNS + ((c >> 3) ^ (r & 7))*8 + (c & 7)];
      }
      *(u16x8*)&Tt[h][c*LSTR + swz(m, c)*8] = v;
    }
    // own-slot T0 registers (this wave's half only)
    u16x4 tcur[5], tprev[5];
#pragma unroll
    for (int mf = 0; mf < 5; ++mf) {
      int r0 = wm*80 + mf*16 + lg*4;
#pragma unroll
      for (int e = 0; e < 4; ++e) {
        int r = r0 + e;
        tcur[mf][e] = Tn[ph][r*TNS + ((cown >> 3) ^ (r & 7))*8 + (cown & 7)];
      }
      tprev[mf] = tcur[mf];
    }
    __syncthreads();
#pragma unroll 1
    for (int t = 0; t < 6; ++t) {
      // ---- weight GEMM, both halves: acc += T_t @ W_t (wave tile 80x32) ----
#pragma unroll
      for (int h = 0; h < 2; ++h) {
        int kbase = t*256 + (qp*2+h)*64;
#pragma unroll
        for (int ks = 0; ks < 64; ks += 32) {
          f16x8 a[5], bv[2];
#pragma unroll
          for (int nf = 0; nf < 2; ++nf)
            bv[nf] = *(const f16x8*)&WT[(size_t)(wn*32 + nf*16 + lr)*1536 + kbase + ks + lg*8];
#pragma unroll
          for (int mf = 0; mf < 5; ++mf) {
            int row = wm*80 + mf*16 + lr;
            int sg = (ks >> 3) + lg;
            a[mf] = *(const f16x8*)&Tn[h][row*TNS + (sg ^ (row & 7))*8];
          }
#pragma unroll
          for (int nf = 0; nf < 2; ++nf)
#pragma unroll
            for (int mf = 0; mf < 5; ++mf)
              acc[mf][nf] = __builtin_amdgcn_mfma_f32_16x16x32_f16(a[mf], bv[nf], acc[mf][nf], 0, 0, 0);
        }
      }
      if (t < 5) {
        // ---- prop MFMA: pacc = L2 @ T_t for this wave's (half, 16-ch slice) ----
        f32x4 pacc[5];
#pragma unroll
        for (int mf = 0; mf < 5; ++mf) pacc[mf] = (f32x4)0.f;
#pragma unroll
        for (int ks = 0; ks < 5; ++ks) {
          int sg = ks*4 + lg;
          f16x8 b = *(const f16x8*)&Tt[ph][cown*LSTR + swz(sg, cown)*8];
#pragma unroll
          for (int mf = 0; mf < 5; ++mf) {
            int row = wm*80 + mf*16 + lr;
            f16x8 a = *(const f16x8*)&Ls[row*LSTR + swz(sg, row)*8];
            pacc[mf] = __builtin_amdgcn_mfma_f32_16x16x32_f16(a, b, pacc[mf], 0, 0, 0);
          }
        }
        __syncthreads();   // all Tn/Tt reads of term t complete
        // epilogue: T_{t+1} = pacc - T_{t-1} (0.5*pacc at t=0); owner-exclusive, in-place
#pragma unroll
        for (int mf = 0; mf < 5; ++mf) {
          int r0 = wm*80 + mf*16 + lg*4;
          u16x4 o;
#pragma unroll
          for (int e = 0; e < 4; ++e) {
            int r = r0 + e;
            float v = (t == 0) ? 0.5f*pacc[mf][e]
                               : pacc[mf][e] - h2f(tprev[mf][e]);
            o[e] = f2h(v);
            Tn[ph][r*TNS + ((cown >> 3) ^ (r & 7))*8 + (cown & 7)] = o[e];
          }
          *(u16x4*)&Tt[ph][cown*LSTR + swz(r0 >> 3, cown)*8 + (r0 & 7)] = o;
          tprev[mf] = tcur[mf];
          tcur[mf] = o;
        }
        __syncthreads();
      }
    }
  }
  // ---- OUT epilogue + fused stats / rowsumsq ----
  if (OMODE == 0) {
#pragma unroll
    for (int nf = 0; nf < 2; ++nf) {
      int col = wn*32 + nf*16 + lr;
      float bc = bCur[col];
      float s = 0.f, s2 = 0.f;
#pragma unroll
      for (int mf = 0; mf < 5; ++mf) {
        int row = wm*80 + mf*16 + lg*4;
#pragma unroll
        for (int e = 0; e < 4; ++e) {
          int r = row + e;
          if (r < PJ) {
            float v = acc[mf][nf][e];
            OUTp[(size_t)(jb+r)*HD + col] = f2h(v);
            float vb = v + bc;
            s += vb; s2 += vb*vb;
          }
        }
      }
      s  += __shfl_xor(s, 16, 64);  s  += __shfl_xor(s, 32, 64);
      s2 += __shfl_xor(s2, 16, 64); s2 += __shfl_xor(s2, 32, 64);
      if (lg == 0) {
        atomicAdd(&statsCur[col], s);
        atomicAdd(&statsCur[HD + col], s2);
      }
    }
  } else {
    float bc[2];
#pragma unroll
    for (int nf = 0; nf < 2; ++nf) bc[nf] = bCur[wn*32 + nf*16 + lr];
#pragma unroll
    for (int mf = 0; mf < 5; ++mf) {
      int row = wm*80 + mf*16 + lg*4;
#pragma unroll
      for (int e = 0; e < 4; ++e) {
        int r = row + e;
        float srow = 0.f;
        if (r < PJ) {
#pragma unroll
          for (int nf = 0; nf < 2; ++nf) {
            int col = wn*32 + nf*16 + lr;
            float v = acc[mf][nf][e];
            OUTp[(size_t)(jb+r)*HD + col] = f2h(v);
            float vb = v + bc[nf];
            srow += vb*vb;
          }
        }
        srow += __shfl_xor(srow, 1, 64);
        srow += __shfl_xor(srow, 2, 64);
        srow += __shfl_xor(srow, 4, 64);
        srow += __shfl_xor(srow, 8, 64);
        if (lr == 0 && r < PJ) atomicAdd(&rn[jb + r], srow);
      }
    }
  }
}

// ---------------- distance softmax pooling, fused row-normalize ----------------

__global__ __launch_bounds__(256) void k_pool(const u16* __restrict__ h, const float* __restrict__ rn,
                                              const float* __restrict__ bias, const float* __restrict__ x,
                                              const float* __restrict__ centers, const float* __restrict__ log_temp,
                                              float* __restrict__ out) {
  __shared__ float a_s[PJ][NCL];
  __shared__ float colsum[NCL];
  __shared__ float inv_s[PJ];
  int j = blockIdx.x;
  int tid = threadIdx.x;
  float T = expf(fminf(fmaxf(log_temp[0], -2.f), 3.f));
  if (tid < PJ) {
    int g = j*PJ + tid;
    inv_s[tid] = 1.f / fmaxf(sqrtf(rn[g]), 1e-12f);
    float eta = x[(size_t)g*3], phi = x[(size_t)g*3 + 1];
    float d[NCL];
    float dmin = 1e30f;
#pragma unroll
    for (int k = 0; k < NCL; ++k) {
      float dx = eta - centers[2*k], dy = phi - centers[2*k+1];
      d[k] = dx*dx + dy*dy;
      dmin = fminf(dmin, d[k]);
    }
    float s = 0.f, ek[NCL];
#pragma unroll
    for (int k = 0; k < NCL; ++k) { ek[k] = expf(-T*(d[k]-dmin)); s += ek[k]; }
    float invs = 1.f/s;
#pragma unroll
    for (int k = 0; k < NCL; ++k) a_s[tid][k] = ek[k]*invs;
  }
  __syncthreads();
  if (tid < NCL) {
    float s = 0.f;
    for (int n = 0; n < PJ; ++n) s += a_s[n][tid];
    colsum[tid] = s;
  }
  __syncthreads();
  int c = tid;
  float bc = bias[c];
  float acc[NCL] = {};
  for (int n = 0; n < PJ; ++n) {
    float hv = (h2f(h[(size_t)(j*PJ + n)*HD + c]) + bc) * inv_s[n];
#pragma unroll
    for (int k = 0; k < NCL; ++k) acc[k] += a_s[n][k]*hv;
  }
#pragma unroll
  for (int k = 0; k < NCL; ++k)
    out[(size_t)j*(NCL*HD) + k*HD + c] = acc[k] / (colsum[k] + 1e-8f);
}

// ---------------- host ----------------

extern "C" void kernel_launch(void* const* d_in, const int* in_sizes, int n_in,
                              void* d_out, int out_size, void* d_ws, size_t ws_size,
                              hipStream_t stream) {
  (void)in_sizes; (void)n_in; (void)out_size;
  const float* x   = (const float*)d_in[0];
  const int*   ei  = (const int*)d_in[1];
  const int*   srcA = ei;
  const int*   tgtA = ei + NEDGE;
  const float* W1  = (const float*)d_in[3];
  const float* b1  = (const float*)d_in[4];
  const float* W2  = (const float*)d_in[5];
  const float* b2  = (const float*)d_in[6];
  const float* W3  = (const float*)d_in[7];
  const float* b3  = (const float*)d_in[8];
  const float* W4  = (const float*)d_in[9];
  const float* b4  = (const float*)d_in[10];
  const float* g1  = (const float*)d_in[11];
  const float* be1 = (const float*)d_in[12];
  const float* g2  = (const float*)d_in[13];
  const float* be2 = (const float*)d_in[14];
  const float* g3  = (const float*)d_in[15];
  const float* be3 = (const float*)d_in[16];
  const float* centers  = (const float*)d_in[17];
  const float* log_temp = (const float*)d_in[18];
  float* out = (float*)d_out;

  auto rb = [](size_t b) { return (b + 255) & ~(size_t)255; };
  size_t need = 3*rb((size_t)NODES*HD*2)            // OUTA, OUTB, Y
              + 3*rb((size_t)NODES*4)               // dis, counts, cursor
              + rb((size_t)(NODES+1)*4)             // rowptr
              + rb((size_t)NEDGE)                   // ccol
              + rb((size_t)NEDGE*4)                 // cw
              + rb((size_t)3*2*HD*4)                // stats x3
              + rb((size_t)NODES*4);                // rn
  fprintf(stderr, "[kernel_launch] ws_size=%zu need=%zu\n", ws_size, need);
  if (d_ws == nullptr || ws_size < need) {
    float code = 1.0e6f + (float)(ws_size >> 20);
    k_diag<<<1, 1, 0, stream>>>(out, code);
    return;
  }

  char* wp = (char*)d_ws;
  auto alloc = [&](size_t b) -> void* {
    void* p = (void*)wp;
    wp += (b + 255) & ~(size_t)255;
    return p;
  };
  u16*   OUTA = (u16*)alloc((size_t)NODES*HD*2);
  u16*   OUTB = (u16*)alloc((size_t)NODES*HD*2);
  u16*   Y    = (u16*)alloc((size_t)NODES*HD*2);
  float* dis  = (float*)alloc((size_t)NODES*4);
  int*   counts = (int*)alloc((size_t)NODES*4);
  int*   cursor = (int*)alloc((size_t)NODES*4);
  int*   rowptr = (int*)alloc((size_t)(NODES+1)*4);
  unsigned char* ccol = (unsigned char*)alloc((size_t)NEDGE);
  float* cw     = (float*)alloc((size_t)NEDGE*4);
  float* stats  = (float*)alloc((size_t)3*2*HD*4);   // [3][512]
  float* rn     = (float*)alloc((size_t)NODES*4);
  // aliases into Y: layer-1 Tall (11 MB) first, then Lg (52.4 MB) + Wcat3 (2.4 MB)
  float* Tall = (float*)Y;
  u16*   Lg   = Y;
  u16*   Wcat = Y + (size_t)NJETS*160*160;
  float* s0 = stats, *s1 = stats + 512, *s2 = stats + 1024;

  // graph preprocessing
  hipMemsetAsync(counts, 0, (size_t)NODES*4, stream);
  k_dis<<<(NODES+255)/256, 256, 0, stream>>>(tgtA, dis);
  k_counts<<<(NEDGE+255)/256, 256, 0, stream>>>(tgtA, counts);
  k_scan<<<(NJETS+255)/256, 256, 0, stream>>>(counts, rowptr, cursor);
  k_fill<<<(NEDGE+255)/256, 256, 0, stream>>>(srcA, tgtA, dis, cursor, ccol, cw);

  // ---- layer 1 (din=3): fused props + small GEMM (+stats) ----
  k_cheb3<<<NJETS, 512, 0, stream>>>(x, rowptr, ccol, cw, Tall);
  hipMemsetAsync(s0, 0, (size_t)2*HD*4, stream);
  k_gemm1<<<NODES/64, 256, 0, stream>>>(Tall, W1, b1, s0, OUTA);

  // ---- dense Laplacian + all W conversions (after layer 1 frees the Y scratch) ----
  k_prepL<<<NJETS, 256, 0, stream>>>(rowptr, ccol, cw, Lg);
  k_prepW3<<<(3*256*1536+255)/256, 256, 0, stream>>>(W2, W3, W4, Wcat);

  // ---- layers 2..4: fused all-MFMA Cheb, BN-on-stage ----
  hipMemsetAsync(s1, 0, (size_t)2*HD*4, stream);
  k_cheb<0><<<NJETS, 1024, 0, stream>>>(OUTA, Wcat,            Lg, s0, g1, be1, b1, b2, s1, rn, OUTB);
  hipMemsetAsync(s2, 0, (size_t)2*HD*4, stream);
  k_cheb<0><<<NJETS, 1024, 0, stream>>>(OUTB, Wcat + 393216,   Lg, s1, g2, be2, b2, b3, s2, rn, OUTA);
  hipMemsetAsync(rn, 0, (size_t)NODES*4, stream);
  k_cheb<1><<<NJETS, 1024, 0, stream>>>(OUTA, Wcat + 2*393216, Lg, s2, g3, be3, b3, b4, s2, rn, OUTB);

  // ---- pooling (fused rownorm) ----
  k_pool<<<NJETS, 256, 0, stream>>>(OUTB, rn, b4, x, centers, log_temp, out);
}

// Round 13
// 1412.336 us; speedup vs baseline: 1.2032x; 1.0447x over previous
//
#include <hip/hip_runtime.h>
#include <cstdio>

#define NODES 153600
#define PJ 150
#define NJETS 1024
#define DEG 16
#define NEDGE (NODES*DEG)
#define HD 256
#define NCL 10

#define LSTR 192   // Ls/Tt row stride (u16): conflicts killed by seg XOR-swizzle
#define TNS  64    // Tn row stride (u16): seg XOR-swizzle

typedef unsigned short u16;  // fp16 bit pattern
typedef _Float16 f16;
typedef f16 f16x8 __attribute__((ext_vector_type(8)));
typedef u16 u16x8 __attribute__((ext_vector_type(8)));
typedef u16 u16x4 __attribute__((ext_vector_type(4)));
typedef float f32x4 __attribute__((ext_vector_type(4)));

__device__ inline float h2f(u16 u) { union { u16 s; f16 h; } v; v.s = u; return (float)v.h; }
__device__ inline u16 f2h(float f) { union { u16 s; f16 h; } v; v.h = (f16)f; return v.s; }
// XOR-swizzle a 16B segment index within its aligned 8-seg (128B) block
__device__ inline int swz(int seg, int key) { return (seg & ~7) | ((seg & 7) ^ (key & 7)); }

// ---------------- diagnostic ----------------
__global__ void k_diag(float* out, float code) {
  if (blockIdx.x == 0 && threadIdx.x == 0) out[0] = code;
}

// ---------------- graph preprocessing ----------------

__global__ __launch_bounds__(256) void k_dis(const int* __restrict__ tgt, float* __restrict__ dis) {
  int n = blockIdx.x*256 + threadIdx.x;
  if (n >= NODES) return;
  int cnt = 0;
#pragma unroll
  for (int j = 0; j < DEG; ++j) cnt += (tgt[n*DEG + j] != n) ? 1 : 0;
  dis[n] = (cnt > 0) ? rsqrtf((float)cnt) : 0.f;
}

__global__ __launch_bounds__(256) void k_counts(const int* __restrict__ tgt, int* __restrict__ counts) {
  int e = blockIdx.x*256 + threadIdx.x;
  if (e >= NEDGE) return;
  atomicAdd(&counts[tgt[e]], 1);
}

__global__ __launch_bounds__(256) void k_scan(const int* __restrict__ counts, int* __restrict__ rowptr, int* __restrict__ cursor) {
  int j = blockIdx.x*256 + threadIdx.x;
  if (j >= NJETS) return;
  int run = j*PJ*DEG;
  for (int l = 0; l < PJ; ++l) {
    int idx = j*PJ + l;
    int cnt = counts[idx];
    rowptr[idx] = run;
    cursor[idx] = run;
    run += cnt;
  }
  if (j == 0) rowptr[NODES] = NEDGE;
}

__global__ __launch_bounds__(256) void k_fill(const int* __restrict__ src_, const int* __restrict__ tgt_,
                                              const float* __restrict__ dis, int* __restrict__ cursor,
                                              unsigned char* __restrict__ ccol, float* __restrict__ cw) {
  int e = blockIdx.x*256 + threadIdx.x;
  if (e >= NEDGE) return;
  int s = src_[e], t = tgt_[e];
  int pos = atomicAdd(&cursor[t], 1);
  ccol[pos] = (unsigned char)(s % PJ);
  cw[pos] = (s != t) ? -(dis[s]*dis[t]) : 0.f;
}

// ---------------- dense per-jet 2*Laplacian: Lg[jet][160][160] f16 ----------------
__global__ __launch_bounds__(256) void k_prepL(const int* __restrict__ rowptr,
                                               const unsigned char* __restrict__ ccol,
                                               const float* __restrict__ cw,
                                               u16* __restrict__ Lg) {
  int j = blockIdx.x, tid = threadIdx.x;
  u16* L = Lg + (size_t)j*160*160;
  if (tid < 160) {
    u16x8 z = {0,0,0,0,0,0,0,0};
    for (int seg = 0; seg < 20; ++seg) *(u16x8*)&L[tid*160 + seg*8] = z;
    if (tid < PJ) {
      int es = rowptr[j*PJ + tid], ee = rowptr[j*PJ + tid + 1];
      u16* row = L + tid*160;
      for (int e = es; e < ee; ++e) {
        int c = (int)ccol[e];
        row[c] = f2h(h2f(row[c]) + 2.f*cw[e]);   // L2 = 2*Lhat
      }
    }
  }
}

// ---------------- layer 1: fused 5 sparse props (din=3), writes Tall[N][18] fp32 ----------------
__global__ __launch_bounds__(512) void k_cheb3(const float* __restrict__ x,
                                               const int* __restrict__ rowptr,
                                               const unsigned char* __restrict__ ccol,
                                               const float* __restrict__ cw,
                                               float* __restrict__ tall) {
  __shared__ float Ta[450], Tb[450];
  __shared__ float cw_s[PJ*DEG];
  __shared__ u16  col_s[PJ*DEG];
  __shared__ int  rp_s[PJ+1];
  int j = blockIdx.x, tid = threadIdx.x;
  int jb = j*PJ, e0 = jb*DEG;
  for (int i = tid; i < PJ*DEG; i += 512) { cw_s[i] = cw[e0+i]; col_s[i] = (u16)ccol[e0+i]; }
  for (int i = tid; i < PJ+1; i += 512) rp_s[i] = rowptr[jb+i] - e0;
  if (tid < 450) Ta[tid] = x[(size_t)jb*3 + tid];
  __syncthreads();
  int r = tid/3, c = tid - r*3;
  float* cur = Ta; float* oth = Tb;
  if (tid < 450) tall[(size_t)(jb+r)*18 + c] = cur[tid];
  for (int t = 1; t < 6; ++t) {
    if (tid < 450) {
      int es = rp_s[r], ee = rp_s[r+1];
      float acc = 0.f;
      for (int e = es; e < ee; ++e) acc += cw_s[e]*cur[(int)col_s[e]*3 + c];
      float v = (t == 1) ? acc : 2.f*acc - oth[tid];
      oth[tid] = v;
      tall[(size_t)(jb+r)*18 + t*3 + c] = v;
    }
    __syncthreads();
    float* tmp = cur; cur = oth; oth = tmp;
  }
}

// out[n,c] = sum_{i<18} Tall[n,i] * W1[i,c]; fused BN stats (with bias b1)
__global__ __launch_bounds__(256) void k_gemm1(const float* __restrict__ tall, const float* __restrict__ W1,
                                               const float* __restrict__ b1, float* __restrict__ stats,
                                               u16* __restrict__ outc) {
  __shared__ float wl[18*256];
  __shared__ float tl[64*18];
  int c = threadIdx.x;
  for (int i = c; i < 18*256; i += 256) wl[i] = W1[i];
  int n0 = blockIdx.x*64;
  __syncthreads();
  for (int i = c; i < 64*18; i += 256) tl[i] = tall[(size_t)n0*18 + i];
  __syncthreads();
  float bc = b1[c];
  float s = 0.f, s2 = 0.f;
  for (int n = 0; n < 64; ++n) {
    float acc = 0.f;
#pragma unroll
    for (int i = 0; i < 18; ++i) acc += tl[n*18 + i] * wl[i*256 + c];
    outc[(size_t)(n0+n)*HD + c] = f2h(acc);
    float vb = acc + bc;
    s += vb; s2 += vb*vb;
  }
  atomicAdd(&stats[c], s);
  atomicAdd(&stats[HD + c], s2);
}

// ---------------- W prep (merged): WT[layer][cout][k] f16, k = term*256 + cin ----------------
__global__ __launch_bounds__(256) void k_prepW3(const float* __restrict__ Wa, const float* __restrict__ Wb,
                                                const float* __restrict__ Wc, u16* __restrict__ WT) {
  int i = blockIdx.x*256 + threadIdx.x;
  if (i >= 3*256*1536) return;
  int layer = i / (256*1536);
  int rem = i - layer*(256*1536);
  int cout = rem / 1536, k = rem - cout*1536;
  int term = k >> 8, cin = k & 255;
  const float* W = (layer == 0) ? Wa : (layer == 1) ? Wb : Wc;
  WT[i] = f2h(W[(size_t)term*65536 + cin*256 + cout]);
}

// ---------------- fused per-jet Chebyshev layer ----------------
// Same as r12 (XOR-swizzled LDS) but T_{t-1}/T_t per-thread state held in NAMED
// u16x4 registers (no arrays -> no scratch demotion, rule #20).
template<int OMODE>
__global__ __launch_bounds__(1024, 4) void k_cheb(const u16* __restrict__ IN,
                                                  const u16* __restrict__ WTu,
                                                  const u16* __restrict__ Lg,
                                                  const float* __restrict__ statsPrev,
                                                  const float* __restrict__ gP,
                                                  const float* __restrict__ beP,
                                                  const float* __restrict__ bP,
                                                  const float* __restrict__ bCur,
                                                  float* __restrict__ statsCur,
                                                  float* __restrict__ rn,
                                                  u16* __restrict__ OUTp) {
  __shared__ u16 Ls[160*LSTR];         // 61.4 KB
  __shared__ u16 Tn[2][160*TNS];       // 41.0 KB
  __shared__ u16 Tt[2][64*LSTR];       // 49.2 KB
  __shared__ float bnA[HD], bnB[HD];   // 2 KB   -> 153.6 KB total
  int j = blockIdx.x, tid = threadIdx.x;
  int jb = j*PJ;
  int lane = tid & 63, wid = tid >> 6;
  int wm = wid >> 3, wn = wid & 7;          // 2(M) x 8(N)
  int lr = lane & 15, lg = lane >> 4;
  int ph = wn >> 2, cs = wn & 3;            // prop: half + 16-ch slice
  int cown = cs*16 + lr;
  const f16* WT = (const f16*)WTu;

  // BN tables: staged value = lrelu(IN*A + B)
  if (tid < HD) {
    const float invN = 1.f/(float)NODES;
    float m = statsPrev[tid]*invN;
    float var = statsPrev[HD+tid]*invN - m*m;
    float A = rsqrtf(var + 1e-5f) * gP[tid];
    bnA[tid] = A;
    bnB[tid] = (bP[tid] - m)*A + beP[tid];
  }
  // stage dense L once (swizzled)
  {
    const u16* src = Lg + (size_t)j*25600;
    for (int i = tid; i < 3200; i += 1024) {
      int row = i/20, seg = i - row*20;
      *(u16x8*)&Ls[row*LSTR + swz(seg,row)*8] = *(const u16x8*)&src[row*160 + seg*8];
    }
  }
  f32x4 acc[5][2];
#pragma unroll
  for (int a = 0; a < 5; ++a)
#pragma unroll
    for (int b = 0; b < 2; ++b) acc[a][b] = (f32x4)0.f;

  // named per-thread T-state (NO arrays)
  u16x4 tc0, tc1, tc2, tc3, tc4, tp0, tp1, tp2, tp3, tp4;

  for (int qp = 0; qp < 2; ++qp) {
    __syncthreads();   // prior-pair reads done; bn/L staged at qp=0
    // stage T0 = lrelu(BN(IN)) for quarters (qp*2, qp*2+1); zero rows 150..159
    for (int i = tid; i < 2560; i += 1024) {
      int h = (i >= 1280) ? 1 : 0;
      int rem = i - h*1280;
      int row = rem >> 3, seg = rem & 7;
      u16x8 o = {0,0,0,0,0,0,0,0};
      if (row < PJ) {
        int c0 = (qp*2+h)*64 + seg*8;
        u16x8 v = *(const u16x8*)&IN[(size_t)(jb+row)*HD + c0];
#pragma unroll
        for (int u = 0; u < 8; ++u) {
          float f = h2f(v[u])*bnA[c0+u] + bnB[c0+u];
          o[u] = f2h((f > 0.f) ? f : 0.01f*f);
        }
      }
      *(u16x8*)&Tn[h][row*TNS + (seg ^ (row & 7))*8] = o;
    }
    __syncthreads();
    // build Ttr (swizzled both sides)
    for (int i = tid; i < 2560; i += 1024) {
      int h = (i >= 1280) ? 1 : 0;
      int rem = i - h*1280;
      int c = rem & 63, m = rem >> 6;
      u16x8 v;
#pragma unroll
      for (int u = 0; u < 8; ++u) {
        int r = m*8 + u;
        v[u] = Tn[h][r*TNS + ((c >> 3) ^ (r & 7))*8 + (c & 7)];
      }
      *(u16x8*)&Tt[h][c*LSTR + swz(m, c)*8] = v;
    }
    // own-slot T0 into named registers (this wave's half only)
#define TINIT(MF, TC, TP) { int r0 = wm*80 + MF*16 + lg*4; u16x4 t; \
    _Pragma("unroll") for (int e = 0; e < 4; ++e) { int r = r0 + e; \
      t[e] = Tn[ph][r*TNS + ((cown >> 3) ^ (r & 7))*8 + (cown & 7)]; } \
    TC = t; TP = t; }
    TINIT(0, tc0, tp0) TINIT(1, tc1, tp1) TINIT(2, tc2, tp2) TINIT(3, tc3, tp3) TINIT(4, tc4, tp4)
#undef TINIT
    __syncthreads();
#pragma unroll 1
    for (int t = 0; t < 6; ++t) {
      // ---- weight GEMM, both halves: acc += T_t @ W_t (wave tile 80x32) ----
#pragma unroll
      for (int h = 0; h < 2; ++h) {
        int kbase = t*256 + (qp*2+h)*64;
#pragma unroll
        for (int ks = 0; ks < 64; ks += 32) {
          f16x8 a[5], bv[2];
#pragma unroll
          for (int nf = 0; nf < 2; ++nf)
            bv[nf] = *(const f16x8*)&WT[(size_t)(wn*32 + nf*16 + lr)*1536 + kbase + ks + lg*8];
#pragma unroll
          for (int mf = 0; mf < 5; ++mf) {
            int row = wm*80 + mf*16 + lr;
            int sg = (ks >> 3) + lg;
            a[mf] = *(const f16x8*)&Tn[h][row*TNS + (sg ^ (row & 7))*8];
          }
#pragma unroll
          for (int nf = 0; nf < 2; ++nf)
#pragma unroll
            for (int mf = 0; mf < 5; ++mf)
              acc[mf][nf] = __builtin_amdgcn_mfma_f32_16x16x32_f16(a[mf], bv[nf], acc[mf][nf], 0, 0, 0);
        }
      }
      if (t < 5) {
        // ---- prop MFMA: pacc = L2 @ T_t for this wave's (half, 16-ch slice) ----
        f32x4 pacc[5];
#pragma unroll
        for (int mf = 0; mf < 5; ++mf) pacc[mf] = (f32x4)0.f;
#pragma unroll
        for (int ks = 0; ks < 5; ++ks) {
          int sg = ks*4 + lg;
          f16x8 b = *(const f16x8*)&Tt[ph][cown*LSTR + swz(sg, cown)*8];
#pragma unroll
          for (int mf = 0; mf < 5; ++mf) {
            int row = wm*80 + mf*16 + lr;
            f16x8 a = *(const f16x8*)&Ls[row*LSTR + swz(sg, row)*8];
            pacc[mf] = __builtin_amdgcn_mfma_f32_16x16x32_f16(a, b, pacc[mf], 0, 0, 0);
          }
        }
        __syncthreads();   // all Tn/Tt reads of term t complete
        // epilogue: T_{t+1} = pacc - T_{t-1} (0.5*pacc at t=0); owner-exclusive, named regs
#define TEPI(MF, TC, TP) { int r0 = wm*80 + MF*16 + lg*4; u16x4 o; \
        _Pragma("unroll") for (int e = 0; e < 4; ++e) { int r = r0 + e; \
          float v = (t == 0) ? 0.5f*pacc[MF][e] : pacc[MF][e] - h2f(TP[e]); \
          o[e] = f2h(v); \
          Tn[ph][r*TNS + ((cown >> 3) ^ (r & 7))*8 + (cown & 7)] = o[e]; } \
        *(u16x4*)&Tt[ph][cown*LSTR + swz(r0 >> 3, cown)*8 + (r0 & 7)] = o; \
        TP = TC; TC = o; }
        TEPI(0, tc0, tp0) TEPI(1, tc1, tp1) TEPI(2, tc2, tp2) TEPI(3, tc3, tp3) TEPI(4, tc4, tp4)
#undef TEPI
        __syncthreads();
      }
    }
  }
  // ---- OUT epilogue + fused stats / rowsumsq ----
  if (OMODE == 0) {
#pragma unroll
    for (int nf = 0; nf < 2; ++nf) {
      int col = wn*32 + nf*16 + lr;
      float bc = bCur[col];
      float s = 0.f, s2 = 0.f;
#pragma unroll
      for (int mf = 0; mf < 5; ++mf) {
        int row = wm*80 + mf*16 + lg*4;
#pragma unroll
        for (int e = 0; e < 4; ++e) {
          int r = row + e;
          if (r < PJ) {
            float v = acc[mf][nf][e];
            OUTp[(size_t)(jb+r)*HD + col] = f2h(v);
            float vb = v + bc;
            s += vb; s2 += vb*vb;
          }
        }
      }
      s  += __shfl_xor(s, 16, 64);  s  += __shfl_xor(s, 32, 64);
      s2 += __shfl_xor(s2, 16, 64); s2 += __shfl_xor(s2, 32, 64);
      if (lg == 0) {
        atomicAdd(&statsCur[col], s);
        atomicAdd(&statsCur[HD + col], s2);
      }
    }
  } else {
    float bc[2];
#pragma unroll
    for (int nf = 0; nf < 2; ++nf) bc[nf] = bCur[wn*32 + nf*16 + lr];
#pragma unroll
    for (int mf = 0; mf < 5; ++mf) {
      int row = wm*80 + mf*16 + lg*4;
#pragma unroll
      for (int e = 0; e < 4; ++e) {
        int r = row + e;
        float srow = 0.f;
        if (r < PJ) {
#pragma unroll
          for (int nf = 0; nf < 2; ++nf) {
            int col = wn*32 + nf*16 + lr;
            float v = acc[mf][nf][e];
            OUTp[(size_t)(jb+r)*HD + col] = f2h(v);
            float vb = v + bc[nf];
            srow += vb*vb;
          }
        }
        srow += __shfl_xor(srow, 1, 64);
        srow += __shfl_xor(srow, 2, 64);
        srow += __shfl_xor(srow, 4, 64);
        srow += __shfl_xor(srow, 8, 64);
        if (lr == 0 && r < PJ) atomicAdd(&rn[jb + r], srow);
      }
    }
  }
}

// ---------------- distance softmax pooling, fused row-normalize ----------------

__global__ __launch_bounds__(256) void k_pool(const u16* __restrict__ h, const float* __restrict__ rn,
                                              const float* __restrict__ bias, const float* __restrict__ x,
                                              const float* __restrict__ centers, const float* __restrict__ log_temp,
                                              float* __restrict__ out) {
  __shared__ float a_s[PJ][NCL];
  __shared__ float colsum[NCL];
  __shared__ float inv_s[PJ];
  int j = blockIdx.x;
  int tid = threadIdx.x;
  float T = expf(fminf(fmaxf(log_temp[0], -2.f), 3.f));
  if (tid < PJ) {
    int g = j*PJ + tid;
    inv_s[tid] = 1.f / fmaxf(sqrtf(rn[g]), 1e-12f);
    float eta = x[(size_t)g*3], phi = x[(size_t)g*3 + 1];
    float d[NCL];
    float dmin = 1e30f;
#pragma unroll
    for (int k = 0; k < NCL; ++k) {
      float dx = eta - centers[2*k], dy = phi - centers[2*k+1];
      d[k] = dx*dx + dy*dy;
      dmin = fminf(dmin, d[k]);
    }
    float s = 0.f, ek[NCL];
#pragma unroll
    for (int k = 0; k < NCL; ++k) { ek[k] = expf(-T*(d[k]-dmin)); s += ek[k]; }
    float invs = 1.f/s;
#pragma unroll
    for (int k = 0; k < NCL; ++k) a_s[tid][k] = ek[k]*invs;
  }
  __syncthreads();
  if (tid < NCL) {
    float s = 0.f;
    for (int n = 0; n < PJ; ++n) s += a_s[n][tid];
    colsum[tid] = s;
  }
  __syncthreads();
  int c = tid;
  float bc = bias[c];
  float acc[NCL] = {};
  for (int n = 0; n < PJ; ++n) {
    float hv = (h2f(h[(size_t)(j*PJ + n)*HD + c]) + bc) * inv_s[n];
#pragma unroll
    for (int k = 0; k < NCL; ++k) acc[k] += a_s[n][k]*hv;
  }
#pragma unroll
  for (int k = 0; k < NCL; ++k)
    out[(size_t)j*(NCL*HD) + k*HD + c] = acc[k] / (colsum[k] + 1e-8f);
}

// ---------------- host ----------------

extern "C" void kernel_launch(void* const* d_in, const int* in_sizes, int n_in,
                              void* d_out, int out_size, void* d_ws, size_t ws_size,
                              hipStream_t stream) {
  (void)in_sizes; (void)n_in; (void)out_size;
  const float* x   = (const float*)d_in[0];
  const int*   ei  = (const int*)d_in[1];
  const int*   srcA = ei;
  const int*   tgtA = ei + NEDGE;
  const float* W1  = (const float*)d_in[3];
  const float* b1  = (const float*)d_in[4];
  const float* W2  = (const float*)d_in[5];
  const float* b2  = (const float*)d_in[6];
  const float* W3  = (const float*)d_in[7];
  const float* b3  = (const float*)d_in[8];
  const float* W4  = (const float*)d_in[9];
  const float* b4  = (const float*)d_in[10];
  const float* g1  = (const float*)d_in[11];
  const float* be1 = (const float*)d_in[12];
  const float* g2  = (const float*)d_in[13];
  const float* be2 = (const float*)d_in[14];
  const float* g3  = (const float*)d_in[15];
  const float* be3 = (const float*)d_in[16];
  const float* centers  = (const float*)d_in[17];
  const float* log_temp = (const float*)d_in[18];
  float* out = (float*)d_out;

  auto rb = [](size_t b) { return (b + 255) & ~(size_t)255; };
  size_t need = 3*rb((size_t)NODES*HD*2)            // OUTA, OUTB, Y
              + 3*rb((size_t)NODES*4)               // dis, counts, cursor
              + rb((size_t)(NODES+1)*4)             // rowptr
              + rb((size_t)NEDGE)                   // ccol
              + rb((size_t)NEDGE*4)                 // cw
              + rb((size_t)3*2*HD*4)                // stats x3
              + rb((size_t)NODES*4);                // rn
  fprintf(stderr, "[kernel_launch] ws_size=%zu need=%zu\n", ws_size, need);
  if (d_ws == nullptr || ws_size < need) {
    float code = 1.0e6f + (float)(ws_size >> 20);
    k_diag<<<1, 1, 0, stream>>>(out, code);
    return;
  }

  char* wp = (char*)d_ws;
  auto alloc = [&](size_t b) -> void* {
    void* p = (void*)wp;
    wp += (b + 255) & ~(size_t)255;
    return p;
  };
  u16*   OUTA = (u16*)alloc((size_t)NODES*HD*2);
  u16*   OUTB = (u16*)alloc((size_t)NODES*HD*2);
  u16*   Y    = (u16*)alloc((size_t)NODES*HD*2);
  float* dis  = (float*)alloc((size_t)NODES*4);
  int*   counts = (int*)alloc((size_t)NODES*4);
  int*   cursor = (int*)alloc((size_t)NODES*4);
  int*   rowptr = (int*)alloc((size_t)(NODES+1)*4);
  unsigned char* ccol = (unsigned char*)alloc((size_t)NEDGE);
  float* cw     = (float*)alloc((size_t)NEDGE*4);
  float* stats  = (float*)alloc((size_t)3*2*HD*4);   // [3][512]
  float* rn     = (float*)alloc((size_t)NODES*4);
  // aliases into Y: layer-1 Tall (11 MB) first, then Lg (52.4 MB) + Wcat3 (2.4 MB)
  float* Tall = (float*)Y;
  u16*   Lg   = Y;
  u16*   Wcat = Y + (size_t)NJETS*160*160;
  float* s0 = stats, *s1 = stats + 512, *s2 = stats + 1024;

  // graph preprocessing
  hipMemsetAsync(counts, 0, (size_t)NODES*4, stream);
  k_dis<<<(NODES+255)/256, 256, 0, stream>>>(tgtA, dis);
  k_counts<<<(NEDGE+255)/256, 256, 0, stream>>>(tgtA, counts);
  k_scan<<<(NJETS+255)/256, 256, 0, stream>>>(counts, rowptr, cursor);
  k_fill<<<(NEDGE+255)/256, 256, 0, stream>>>(srcA, tgtA, dis, cursor, ccol, cw);

  // ---- layer 1 (din=3): fused props + small GEMM (+stats) ----
  k_cheb3<<<NJETS, 512, 0, stream>>>(x, rowptr, ccol, cw, Tall);
  hipMemsetAsync(s0, 0, (size_t)2*HD*4, stream);
  k_gemm1<<<NODES/64, 256, 0, stream>>>(Tall, W1, b1, s0, OUTA);

  // ---- dense Laplacian + all W conversions (after layer 1 frees the Y scratch) ----
  k_prepL<<<NJETS, 256, 0, stream>>>(rowptr, ccol, cw, Lg);
  k_prepW3<<<(3*256*1536+255)/256, 256, 0, stream>>>(W2, W3, W4, Wcat);

  // ---- layers 2..4: fused all-MFMA Cheb, BN-on-stage ----
  hipMemsetAsync(s1, 0, (size_t)2*HD*4, stream);
  k_cheb<0><<<NJETS, 1024, 0, stream>>>(OUTA, Wcat,            Lg, s0, g1, be1, b1, b2, s1, rn, OUTB);
  hipMemsetAsync(s2, 0, (size_t)2*HD*4, stream);
  k_cheb<0><<<NJETS, 1024, 0, stream>>>(OUTB, Wcat + 393216,   Lg, s1, g2, be2, b2, b3, s2, rn, OUTA);
  hipMemsetAsync(rn, 0, (size_t)NODES*4, stream);
  k_cheb<1><<<NJETS, 1024, 0, stream>>>(OUTA, Wcat + 2*393216, Lg, s2, g3, be3, b3, b4, s2, rn, OUTB);

  // ---- pooling (fused rownorm) ----
  k_pool<<<NJETS, 256, 0, stream>>>(OUTB, rn, b4, x, centers, log_temp, out);
}

// Round 14
// 1351.372 us; speedup vs baseline: 1.2575x; 1.0451x over previous
//
#include <hip/hip_runtime.h>
#include <cstdio>

#define NODES 153600
#define PJ 150
#define NJETS 1024
#define DEG 16
#define NEDGE (NODES*DEG)
#define HD 256
#define NCL 10

#define LSTR 192   // Ls/Tt row stride (u16): conflicts killed by seg XOR-swizzle (key = lr&7)
#define TNS  64    // Tn row stride (u16): seg XOR-swizzle (key = lr&7)

typedef unsigned short u16;  // fp16 bit pattern
typedef _Float16 f16;
typedef f16 f16x8 __attribute__((ext_vector_type(8)));
typedef u16 u16x8 __attribute__((ext_vector_type(8)));
typedef u16 u16x4 __attribute__((ext_vector_type(4)));
typedef float f32x4 __attribute__((ext_vector_type(4)));

__device__ inline float h2f(u16 u) { union { u16 s; f16 h; } v; v.s = u; return (float)v.h; }
__device__ inline u16 f2h(float f) { union { u16 s; f16 h; } v; v.h = (f16)f; return v.s; }
// XOR-swizzle a 16B segment index within its aligned 8-seg (128B) block
__device__ inline int swz(int seg, int key) { return (seg & ~7) | ((seg & 7) ^ (key & 7)); }

// ---------------- diagnostic ----------------
__global__ void k_diag(float* out, float code) {
  if (blockIdx.x == 0 && threadIdx.x == 0) out[0] = code;
}

// ---------------- graph preprocessing ----------------

__global__ __launch_bounds__(256) void k_discounts(const int* __restrict__ tgt,
                                                   int* __restrict__ counts,
                                                   float* __restrict__ dis) {
  int i = blockIdx.x*256 + threadIdx.x;
  if (i < NEDGE) atomicAdd(&counts[tgt[i]], 1);
  if (i < NODES) {
    int cnt = 0;
#pragma unroll
    for (int j = 0; j < DEG; ++j) cnt += (tgt[i*DEG + j] != i) ? 1 : 0;
    dis[i] = (cnt > 0) ? rsqrtf((float)cnt) : 0.f;
  }
}

__global__ __launch_bounds__(256) void k_scan(const int* __restrict__ counts, int* __restrict__ rowptr, int* __restrict__ cursor) {
  int j = blockIdx.x*256 + threadIdx.x;
  if (j >= NJETS) return;
  int run = j*PJ*DEG;
  for (int l = 0; l < PJ; ++l) {
    int idx = j*PJ + l;
    int cnt = counts[idx];
    rowptr[idx] = run;
    cursor[idx] = run;
    run += cnt;
  }
  if (j == 0) rowptr[NODES] = NEDGE;
}

__global__ __launch_bounds__(256) void k_fill(const int* __restrict__ src_, const int* __restrict__ tgt_,
                                              const float* __restrict__ dis, int* __restrict__ cursor,
                                              unsigned char* __restrict__ ccol, float* __restrict__ cw) {
  int e = blockIdx.x*256 + threadIdx.x;
  if (e >= NEDGE) return;
  int s = src_[e], t = tgt_[e];
  int pos = atomicAdd(&cursor[t], 1);
  ccol[pos] = (unsigned char)(s % PJ);
  cw[pos] = (s != t) ? -(dis[s]*dis[t]) : 0.f;
}

// ---------------- merged: dense per-jet 2*Laplacian + W conversion + zeroing ----------------
// blocks [0, NJETS): prepL for jet = bid. blocks [NJETS, NJETS+4608): prepW3 + s1/s2/rn zero.
__global__ __launch_bounds__(256) void k_prepLW(const int* __restrict__ rowptr,
                                                const unsigned char* __restrict__ ccol,
                                                const float* __restrict__ cw,
                                                u16* __restrict__ Lg,
                                                const float* __restrict__ Wa, const float* __restrict__ Wb,
                                                const float* __restrict__ Wc, u16* __restrict__ WT,
                                                float* __restrict__ s1, float* __restrict__ s2,
                                                float* __restrict__ rn) {
  int bid = blockIdx.x, tid = threadIdx.x;
  if (bid < NJETS) {
    int j = bid;
    u16* L = Lg + (size_t)j*160*160;
    if (tid < 160) {
      u16x8 z = {0,0,0,0,0,0,0,0};
      for (int seg = 0; seg < 20; ++seg) *(u16x8*)&L[tid*160 + seg*8] = z;
      if (tid < PJ) {
        int es = rowptr[j*PJ + tid], ee = rowptr[j*PJ + tid + 1];
        u16* row = L + tid*160;
        for (int e = es; e < ee; ++e) {
          int c = (int)ccol[e];
          row[c] = f2h(h2f(row[c]) + 2.f*cw[e]);   // L2 = 2*Lhat
        }
      }
    }
  } else {
    int i = (bid - NJETS)*256 + tid;
    if (i < 3*256*1536) {
      int layer = i / (256*1536);
      int rem = i - layer*(256*1536);
      int cout = rem / 1536, k = rem - cout*1536;
      int term = k >> 8, cin = k & 255;
      const float* W = (layer == 0) ? Wa : (layer == 1) ? Wb : Wc;
      WT[i] = f2h(W[(size_t)term*65536 + cin*256 + cout]);
    }
    if (i < 2*HD) { s1[i] = 0.f; s2[i] = 0.f; }
    if (i < NODES) rn[i] = 0.f;
  }
}

// ---------------- layer 1: fused 5 sparse props (din=3), writes Tall[N][18] fp32 ----------------
__global__ __launch_bounds__(512) void k_cheb3(const float* __restrict__ x,
                                               const int* __restrict__ rowptr,
                                               const unsigned char* __restrict__ ccol,
                                               const float* __restrict__ cw,
                                               float* __restrict__ tall,
                                               float* __restrict__ s0) {
  __shared__ float Ta[450], Tb[450];
  __shared__ float cw_s[PJ*DEG];
  __shared__ u16  col_s[PJ*DEG];
  __shared__ int  rp_s[PJ+1];
  int j = blockIdx.x, tid = threadIdx.x;
  if (j == 0 && tid < 2*HD) s0[tid] = 0.f;   // zero layer-1 BN stats (consumed next kernel)
  int jb = j*PJ, e0 = jb*DEG;
  for (int i = tid; i < PJ*DEG; i += 512) { cw_s[i] = cw[e0+i]; col_s[i] = (u16)ccol[e0+i]; }
  for (int i = tid; i < PJ+1; i += 512) rp_s[i] = rowptr[jb+i] - e0;
  if (tid < 450) Ta[tid] = x[(size_t)jb*3 + tid];
  __syncthreads();
  int r = tid/3, c = tid - r*3;
  float* cur = Ta; float* oth = Tb;
  if (tid < 450) tall[(size_t)(jb+r)*18 + c] = cur[tid];
  for (int t = 1; t < 6; ++t) {
    if (tid < 450) {
      int es = rp_s[r], ee = rp_s[r+1];
      float acc = 0.f;
      for (int e = es; e < ee; ++e) acc += cw_s[e]*cur[(int)col_s[e]*3 + c];
      float v = (t == 1) ? acc : 2.f*acc - oth[tid];
      oth[tid] = v;
      tall[(size_t)(jb+r)*18 + t*3 + c] = v;
    }
    __syncthreads();
    float* tmp = cur; cur = oth; oth = tmp;
  }
}

// out[n,c] = sum_{i<18} Tall[n,i] * W1[i,c]; fused BN stats (with bias b1)
__global__ __launch_bounds__(256) void k_gemm1(const float* __restrict__ tall, const float* __restrict__ W1,
                                               const float* __restrict__ b1, float* __restrict__ stats,
                                               u16* __restrict__ outc) {
  __shared__ float wl[18*256];
  __shared__ float tl[64*18];
  int c = threadIdx.x;
  for (int i = c; i < 18*256; i += 256) wl[i] = W1[i];
  int n0 = blockIdx.x*64;
  __syncthreads();
  for (int i = c; i < 64*18; i += 256) tl[i] = tall[(size_t)n0*18 + i];
  __syncthreads();
  float bc = b1[c];
  float s = 0.f, s2 = 0.f;
  for (int n = 0; n < 64; ++n) {
    float acc = 0.f;
#pragma unroll
    for (int i = 0; i < 18; ++i) acc += tl[n*18 + i] * wl[i*256 + c];
    outc[(size_t)(n0+n)*HD + c] = f2h(acc);
    float vb = acc + bc;
    s += vb; s2 += vb*vb;
  }
  atomicAdd(&stats[c], s);
  atomicAdd(&stats[HD + c], s2);
}

// ---------------- fused per-jet Chebyshev layer ----------------
// r13 structure (XOR-swizzled LDS, named T-state regs) with all hot-loop swizzle
// keys hoisted: row&7 == cown&7 == lr&7 (80,16 ≡ 0 mod 8) -> thread-invariant offsets.
template<int OMODE>
__global__ __launch_bounds__(1024, 4) void k_cheb(const u16* __restrict__ IN,
                                                  const u16* __restrict__ WTu,
                                                  const u16* __restrict__ Lg,
                                                  const float* __restrict__ statsPrev,
                                                  const float* __restrict__ gP,
                                                  const float* __restrict__ beP,
                                                  const float* __restrict__ bP,
                                                  const float* __restrict__ bCur,
                                                  float* __restrict__ statsCur,
                                                  float* __restrict__ rn,
                                                  u16* __restrict__ OUTp) {
  __shared__ u16 Ls[160*LSTR];         // 61.4 KB
  __shared__ u16 Tn[2][160*TNS];       // 41.0 KB
  __shared__ u16 Tt[2][64*LSTR];       // 49.2 KB
  __shared__ float bnA[HD], bnB[HD];   // 2 KB   -> 153.6 KB total
  int j = blockIdx.x, tid = threadIdx.x;
  int jb = j*PJ;
  int lane = tid & 63, wid = tid >> 6;
  int wm = wid >> 3, wn = wid & 7;          // 2(M) x 8(N)
  int lr = lane & 15, lg = lane >> 4;
  int ph = wn >> 2, cs = wn & 3;            // prop: half + 16-ch slice
  int cown = cs*16 + lr;
  // ---- hoisted thread-invariant swizzle offsets (u16 units) ----
  int key   = lr & 7;
  int segA0 = ((lg    ) ^ key) * 8;         // seg block 0 (sg&~7 == 0)
  int segA1 = ((lg + 4) ^ key) * 8;         // seg block 0, sg&7 = lg+4
  int pOff[5] = { segA0, segA1, 64 + segA0, 64 + segA1, 128 + segA0 };  // prop ks 0..4
  int ep0 = ((cown >> 3) ^ ((lg & 1)*4 + 0)) * 8 + (cown & 7);
  int ep1 = ((cown >> 3) ^ ((lg & 1)*4 + 1)) * 8 + (cown & 7);
  int ep2 = ((cown >> 3) ^ ((lg & 1)*4 + 2)) * 8 + (cown & 7);
  int ep3 = ((cown >> 3) ^ ((lg & 1)*4 + 3)) * 8 + (cown & 7);
  int cownL = cown * LSTR;
  const f16* WT = (const f16*)WTu;
  const f16* wtb = WT + (size_t)(wn*32 + lr)*1536 + lg*8;   // + nf*16*1536 + kbase + ks

  // BN tables: staged value = lrelu(IN*A + B)
  if (tid < HD) {
    const float invN = 1.f/(float)NODES;
    float m = statsPrev[tid]*invN;
    float var = statsPrev[HD+tid]*invN - m*m;
    float A = rsqrtf(var + 1e-5f) * gP[tid];
    bnA[tid] = A;
    bnB[tid] = (bP[tid] - m)*A + beP[tid];
  }
  // stage dense L once (swizzled; cold path keeps generic swz)
  {
    const u16* src = Lg + (size_t)j*25600;
    for (int i = tid; i < 3200; i += 1024) {
      int row = i/20, seg = i - row*20;
      *(u16x8*)&Ls[row*LSTR + swz(seg,row)*8] = *(const u16x8*)&src[row*160 + seg*8];
    }
  }
  f32x4 acc[5][2];
#pragma unroll
  for (int a = 0; a < 5; ++a)
#pragma unroll
    for (int b = 0; b < 2; ++b) acc[a][b] = (f32x4)0.f;

  // named per-thread T-state (NO arrays)
  u16x4 tc0, tc1, tc2, tc3, tc4, tp0, tp1, tp2, tp3, tp4;

  for (int qp = 0; qp < 2; ++qp) {
    __syncthreads();   // prior-pair reads done; bn/L staged at qp=0
    // stage T0 = lrelu(BN(IN)) for quarters (qp*2, qp*2+1); zero rows 150..159
    for (int i = tid; i < 2560; i += 1024) {
      int h = (i >= 1280) ? 1 : 0;
      int rem = i - h*1280;
      int row = rem >> 3, seg = rem & 7;
      u16x8 o = {0,0,0,0,0,0,0,0};
      if (row < PJ) {
        int c0 = (qp*2+h)*64 + seg*8;
        u16x8 v = *(const u16x8*)&IN[(size_t)(jb+row)*HD + c0];
#pragma unroll
        for (int u = 0; u < 8; ++u) {
          float f = h2f(v[u])*bnA[c0+u] + bnB[c0+u];
          o[u] = f2h((f > 0.f) ? f : 0.01f*f);
        }
      }
      *(u16x8*)&Tn[h][row*TNS + (seg ^ (row & 7))*8] = o;
    }
    __syncthreads();
    // build Ttr (swizzled both sides; cold path)
    for (int i = tid; i < 2560; i += 1024) {
      int h = (i >= 1280) ? 1 : 0;
      int rem = i - h*1280;
      int c = rem & 63, m = rem >> 6;
      u16x8 v;
#pragma unroll
      for (int u = 0; u < 8; ++u) {
        int r = m*8 + u;
        v[u] = Tn[h][r*TNS + ((c >> 3) ^ (r & 7))*8 + (c & 7)];
      }
      *(u16x8*)&Tt[h][c*LSTR + swz(m, c)*8] = v;
    }
    // own-slot T0 into named registers (this wave's half only)
#define TINIT(MF, TC, TP) { int r0 = wm*80 + MF*16 + lg*4; u16x4 t; \
    t[0] = Tn[ph][(r0+0)*TNS + ep0]; t[1] = Tn[ph][(r0+1)*TNS + ep1]; \
    t[2] = Tn[ph][(r0+2)*TNS + ep2]; t[3] = Tn[ph][(r0+3)*TNS + ep3]; \
    TC = t; TP = t; }
    TINIT(0, tc0, tp0) TINIT(1, tc1, tp1) TINIT(2, tc2, tp2) TINIT(3, tc3, tp3) TINIT(4, tc4, tp4)
#undef TINIT
    __syncthreads();
#pragma unroll 1
    for (int t = 0; t < 6; ++t) {
      // ---- weight GEMM, both halves: acc += T_t @ W_t (wave tile 80x32) ----
#pragma unroll
      for (int h = 0; h < 2; ++h) {
        int kbase = t*256 + (qp*2+h)*64;
#pragma unroll
        for (int ks = 0; ks < 64; ks += 32) {
          int segA = (ks == 0) ? segA0 : segA1;
          f16x8 a[5], bv[2];
#pragma unroll
          for (int nf = 0; nf < 2; ++nf)
            bv[nf] = *(const f16x8*)&wtb[nf*24576 + kbase + ks];
#pragma unroll
          for (int mf = 0; mf < 5; ++mf) {
            int row = wm*80 + mf*16 + lr;
            a[mf] = *(const f16x8*)&Tn[h][row*TNS + segA];
          }
#pragma unroll
          for (int nf = 0; nf < 2; ++nf)
#pragma unroll
            for (int mf = 0; mf < 5; ++mf)
              acc[mf][nf] = __builtin_amdgcn_mfma_f32_16x16x32_f16(a[mf], bv[nf], acc[mf][nf], 0, 0, 0);
        }
      }
      if (t < 5) {
        // ---- prop MFMA: pacc = L2 @ T_t for this wave's (half, 16-ch slice) ----
        f32x4 pacc[5];
#pragma unroll
        for (int mf = 0; mf < 5; ++mf) pacc[mf] = (f32x4)0.f;
#pragma unroll
        for (int ks = 0; ks < 5; ++ks) {
          f16x8 b = *(const f16x8*)&Tt[ph][cownL + pOff[ks]];
#pragma unroll
          for (int mf = 0; mf < 5; ++mf) {
            int row = wm*80 + mf*16 + lr;
            f16x8 a = *(const f16x8*)&Ls[row*LSTR + pOff[ks]];
            pacc[mf] = __builtin_amdgcn_mfma_f32_16x16x32_f16(a, b, pacc[mf], 0, 0, 0);
          }
        }
        __syncthreads();   // all Tn/Tt reads of term t complete
        // epilogue: T_{t+1} = pacc - T_{t-1} (0.5*pacc at t=0); owner-exclusive, named regs
#define TEPI(MF, TC, TP) { int r0 = wm*80 + MF*16 + lg*4; u16x4 o; \
        { float v0_ = (t == 0) ? 0.5f*pacc[MF][0] : pacc[MF][0] - h2f(TP[0]); o[0] = f2h(v0_); } \
        { float v1_ = (t == 0) ? 0.5f*pacc[MF][1] : pacc[MF][1] - h2f(TP[1]); o[1] = f2h(v1_); } \
        { float v2_ = (t == 0) ? 0.5f*pacc[MF][2] : pacc[MF][2] - h2f(TP[2]); o[2] = f2h(v2_); } \
        { float v3_ = (t == 0) ? 0.5f*pacc[MF][3] : pacc[MF][3] - h2f(TP[3]); o[3] = f2h(v3_); } \
        Tn[ph][(r0+0)*TNS + ep0] = o[0]; Tn[ph][(r0+1)*TNS + ep1] = o[1]; \
        Tn[ph][(r0+2)*TNS + ep2] = o[2]; Tn[ph][(r0+3)*TNS + ep3] = o[3]; \
        int sgT = wm*10 + MF*2 + (lg >> 1); \
        int segT = (sgT & ~7) | ((sgT & 7) ^ key); \
        *(u16x4*)&Tt[ph][cownL + segT*8 + (lg & 1)*4] = o; \
        TP = TC; TC = o; }
        TEPI(0, tc0, tp0) TEPI(1, tc1, tp1) TEPI(2, tc2, tp2) TEPI(3, tc3, tp3) TEPI(4, tc4, tp4)
#undef TEPI
        __syncthreads();
      }
    }
  }
  // ---- OUT epilogue + fused stats / rowsumsq ----
  if (OMODE == 0) {
#pragma unroll
    for (int nf = 0; nf < 2; ++nf) {
      int col = wn*32 + nf*16 + lr;
      float bc = bCur[col];
      float s = 0.f, s2 = 0.f;
#pragma unroll
      for (int mf = 0; mf < 5; ++mf) {
        int row = wm*80 + mf*16 + lg*4;
#pragma unroll
        for (int e = 0; e < 4; ++e) {
          int r = row + e;
          if (r < PJ) {
            float v = acc[mf][nf][e];
            OUTp[(size_t)(jb+r)*HD + col] = f2h(v);
            float vb = v + bc;
            s += vb; s2 += vb*vb;
          }
        }
      }
      s  += __shfl_xor(s, 16, 64);  s  += __shfl_xor(s, 32, 64);
      s2 += __shfl_xor(s2, 16, 64); s2 += __shfl_xor(s2, 32, 64);
      if (lg == 0) {
        atomicAdd(&statsCur[col], s);
        atomicAdd(&statsCur[HD + col], s2);
      }
    }
  } else {
    float bc[2];
#pragma unroll
    for (int nf = 0; nf < 2; ++nf) bc[nf] = bCur[wn*32 + nf*16 + lr];
#pragma unroll
    for (int mf = 0; mf < 5; ++mf) {
      int row = wm*80 + mf*16 + lg*4;
#pragma unroll
      for (int e = 0; e < 4; ++e) {
        int r = row + e;
        float srow = 0.f;
        if (r < PJ) {
#pragma unroll
          for (int nf = 0; nf < 2; ++nf) {
            int col = wn*32 + nf*16 + lr;
            float v = acc[mf][nf][e];
            OUTp[(size_t)(jb+r)*HD + col] = f2h(v);
            float vb = v + bc[nf];
            srow += vb*vb;
          }
        }
        srow += __shfl_xor(srow, 1, 64);
        srow += __shfl_xor(srow, 2, 64);
        srow += __shfl_xor(srow, 4, 64);
        srow += __shfl_xor(srow, 8, 64);
        if (lr == 0 && r < PJ) atomicAdd(&rn[jb + r], srow);
      }
    }
  }
}

// ---------------- distance softmax pooling, fused row-normalize ----------------

__global__ __launch_bounds__(256) void k_pool(const u16* __restrict__ h, const float* __restrict__ rn,
                                              const float* __restrict__ bias, const float* __restrict__ x,
                                              const float* __restrict__ centers, const float* __restrict__ log_temp,
                                              float* __restrict__ out) {
  __shared__ float a_s[PJ][NCL];
  __shared__ float colsum[NCL];
  __shared__ float inv_s[PJ];
  int j = blockIdx.x;
  int tid = threadIdx.x;
  float T = expf(fminf(fmaxf(log_temp[0], -2.f), 3.f));
  if (tid < PJ) {
    int g = j*PJ + tid;
    inv_s[tid] = 1.f / fmaxf(sqrtf(rn[g]), 1e-12f);
    float eta = x[(size_t)g*3], phi = x[(size_t)g*3 + 1];
    float d[NCL];
    float dmin = 1e30f;
#pragma unroll
    for (int k = 0; k < NCL; ++k) {
      float dx = eta - centers[2*k], dy = phi - centers[2*k+1];
      d[k] = dx*dx + dy*dy;
      dmin = fminf(dmin, d[k]);
    }
    float s = 0.f, ek[NCL];
#pragma unroll
    for (int k = 0; k < NCL; ++k) { ek[k] = expf(-T*(d[k]-dmin)); s += ek[k]; }
    float invs = 1.f/s;
#pragma unroll
    for (int k = 0; k < NCL; ++k) a_s[tid][k] = ek[k]*invs;
  }
  __syncthreads();
  if (tid < NCL) {
    float s = 0.f;
    for (int n = 0; n < PJ; ++n) s += a_s[n][tid];
    colsum[tid] = s;
  }
  __syncthreads();
  int c = tid;
  float bc = bias[c];
  float acc[NCL] = {};
  for (int n = 0; n < PJ; ++n) {
    float hv = (h2f(h[(size_t)(j*PJ + n)*HD + c]) + bc) * inv_s[n];
#pragma unroll
    for (int k = 0; k < NCL; ++k) acc[k] += a_s[n][k]*hv;
  }
#pragma unroll
  for (int k = 0; k < NCL; ++k)
    out[(size_t)j*(NCL*HD) + k*HD + c] = acc[k] / (colsum[k] + 1e-8f);
}

// ---------------- host ----------------

extern "C" void kernel_launch(void* const* d_in, const int* in_sizes, int n_in,
                              void* d_out, int out_size, void* d_ws, size_t ws_size,
                              hipStream_t stream) {
  (void)in_sizes; (void)n_in; (void)out_size;
  const float* x   = (const float*)d_in[0];
  const int*   ei  = (const int*)d_in[1];
  const int*   srcA = ei;
  const int*   tgtA = ei + NEDGE;
  const float* W1  = (const float*)d_in[3];
  const float* b1  = (const float*)d_in[4];
  const float* W2  = (const float*)d_in[5];
  const float* b2  = (const float*)d_in[6];
  const float* W3  = (const float*)d_in[7];
  const float* b3  = (const float*)d_in[8];
  const float* W4  = (const float*)d_in[9];
  const float* b4  = (const float*)d_in[10];
  const float* g1  = (const float*)d_in[11];
  const float* be1 = (const float*)d_in[12];
  const float* g2  = (const float*)d_in[13];
  const float* be2 = (const float*)d_in[14];
  const float* g3  = (const float*)d_in[15];
  const float* be3 = (const float*)d_in[16];
  const float* centers  = (const float*)d_in[17];
  const float* log_temp = (const float*)d_in[18];
  float* out = (float*)d_out;

  auto rb = [](size_t b) { return (b + 255) & ~(size_t)255; };
  size_t need = 3*rb((size_t)NODES*HD*2)            // OUTA, OUTB, Y
              + 3*rb((size_t)NODES*4)               // dis, counts, cursor
              + rb((size_t)(NODES+1)*4)             // rowptr
              + rb((size_t)NEDGE)                   // ccol
              + rb((size_t)NEDGE*4)                 // cw
              + rb((size_t)3*2*HD*4)                // stats x3
              + rb((size_t)NODES*4);                // rn
  fprintf(stderr, "[kernel_launch] ws_size=%zu need=%zu\n", ws_size, need);
  if (d_ws == nullptr || ws_size < need) {
    float code = 1.0e6f + (float)(ws_size >> 20);
    k_diag<<<1, 1, 0, stream>>>(out, code);
    return;
  }

  char* wp = (char*)d_ws;
  auto alloc = [&](size_t b) -> void* {
    void* p = (void*)wp;
    wp += (b + 255) & ~(size_t)255;
    return p;
  };
  u16*   OUTA = (u16*)alloc((size_t)NODES*HD*2);
  u16*   OUTB = (u16*)alloc((size_t)NODES*HD*2);
  u16*   Y    = (u16*)alloc((size_t)NODES*HD*2);
  float* dis  = (float*)alloc((size_t)NODES*4);
  int*   counts = (int*)alloc((size_t)NODES*4);
  int*   cursor = (int*)alloc((size_t)NODES*4);
  int*   rowptr = (int*)alloc((size_t)(NODES+1)*4);
  unsigned char* ccol = (unsigned char*)alloc((size_t)NEDGE);
  float* cw     = (float*)alloc((size_t)NEDGE*4);
  float* stats  = (float*)alloc((size_t)3*2*HD*4);   // [3][512]
  float* rn     = (float*)alloc((size_t)NODES*4);
  // aliases into Y: layer-1 Tall (11 MB) first, then Lg (52.4 MB) + Wcat3 (2.4 MB)
  float* Tall = (float*)Y;
  u16*   Lg   = Y;
  u16*   Wcat = Y + (size_t)NJETS*160*160;
  float* s0 = stats, *s1 = stats + 512, *s2 = stats + 1024;

  // graph preprocessing
  hipMemsetAsync(counts, 0, (size_t)NODES*4, stream);
  k_discounts<<<(NEDGE+255)/256, 256, 0, stream>>>(tgtA, counts, dis);
  k_scan<<<(NJETS+255)/256, 256, 0, stream>>>(counts, rowptr, cursor);
  k_fill<<<(NEDGE+255)/256, 256, 0, stream>>>(srcA, tgtA, dis, cursor, ccol, cw);

  // ---- layer 1 (din=3): fused props (+s0 zero) + small GEMM (+stats) ----
  k_cheb3<<<NJETS, 512, 0, stream>>>(x, rowptr, ccol, cw, Tall, s0);
  k_gemm1<<<NODES/64, 256, 0, stream>>>(Tall, W1, b1, s0, OUTA);

  // ---- dense Laplacian + W conversions + s1/s2/rn zeroing (after layer 1 frees Y) ----
  k_prepLW<<<NJETS + (3*256*1536+255)/256, 256, 0, stream>>>(rowptr, ccol, cw, Lg,
                                                             W2, W3, W4, Wcat, s1, s2, rn);

  // ---- layers 2..4: fused all-MFMA Cheb, BN-on-stage ----
  k_cheb<0><<<NJETS, 1024, 0, stream>>>(OUTA, Wcat,            Lg, s0, g1, be1, b1, b2, s1, rn, OUTB);
  k_cheb<0><<<NJETS, 1024, 0, stream>>>(OUTB, Wcat + 393216,   Lg, s1, g2, be2, b2, b3, s2, rn, OUTA);
  k_cheb<1><<<NJETS, 1024, 0, stream>>>(OUTA, Wcat + 2*393216, Lg, s2, g3, be3, b3, b4, s2, rn, OUTB);

  // ---- pooling (fused rownorm) ----
  k_pool<<<NJETS, 256, 0, stream>>>(OUTB, rn, b4, x, centers, log_temp, out);
}

// Round 15
// 1273.049 us; speedup vs baseline: 1.3348x; 1.0615x over previous
//
#include <hip/hip_runtime.h>
#include <cstdio>

#define NODES 153600
#define PJ 150
#define NJETS 1024
#define DEG 16
#define NEDGE (NODES*DEG)
#define HD 256
#define NCL 10

#define LSTR 192   // Ls/Tt row stride (u16): conflicts killed by seg XOR-swizzle (key = lr&7)
#define TNS  64    // Tn row stride (u16): seg XOR-swizzle (key = lr&7)

typedef unsigned short u16;  // fp16 bit pattern
typedef _Float16 f16;
typedef f16 f16x8 __attribute__((ext_vector_type(8)));
typedef u16 u16x8 __attribute__((ext_vector_type(8)));
typedef u16 u16x4 __attribute__((ext_vector_type(4)));
typedef float f32x4 __attribute__((ext_vector_type(4)));

__device__ inline float h2f(u16 u) { union { u16 s; f16 h; } v; v.s = u; return (float)v.h; }
__device__ inline u16 f2h(float f) { union { u16 s; f16 h; } v; v.h = (f16)f; return v.s; }
// XOR-swizzle a 16B segment index within its aligned 8-seg (128B) block
__device__ inline int swz(int seg, int key) { return (seg & ~7) | ((seg & 7) ^ (key & 7)); }

// ---------------- diagnostic ----------------
__global__ void k_diag(float* out, float code) {
  if (blockIdx.x == 0 && threadIdx.x == 0) out[0] = code;
}

// ---------------- graph preprocessing ----------------

__global__ __launch_bounds__(256) void k_discounts(const int* __restrict__ tgt,
                                                   int* __restrict__ counts,
                                                   float* __restrict__ dis) {
  int i = blockIdx.x*256 + threadIdx.x;
  if (i < NEDGE) atomicAdd(&counts[tgt[i]], 1);
  if (i < NODES) {
    int cnt = 0;
#pragma unroll
    for (int j = 0; j < DEG; ++j) cnt += (tgt[i*DEG + j] != i) ? 1 : 0;
    dis[i] = (cnt > 0) ? rsqrtf((float)cnt) : 0.f;
  }
}

__global__ __launch_bounds__(256) void k_scan(const int* __restrict__ counts, int* __restrict__ rowptr, int* __restrict__ cursor) {
  int j = blockIdx.x*256 + threadIdx.x;
  if (j >= NJETS) return;
  int run = j*PJ*DEG;
  for (int l = 0; l < PJ; ++l) {
    int idx = j*PJ + l;
    int cnt = counts[idx];
    rowptr[idx] = run;
    cursor[idx] = run;
    run += cnt;
  }
  if (j == 0) rowptr[NODES] = NEDGE;
}

__global__ __launch_bounds__(256) void k_fill(const int* __restrict__ src_, const int* __restrict__ tgt_,
                                              const float* __restrict__ dis, int* __restrict__ cursor,
                                              unsigned char* __restrict__ ccol, float* __restrict__ cw) {
  int e = blockIdx.x*256 + threadIdx.x;
  if (e >= NEDGE) return;
  int s = src_[e], t = tgt_[e];
  int pos = atomicAdd(&cursor[t], 1);
  ccol[pos] = (unsigned char)(s % PJ);
  cw[pos] = (s != t) ? -(dis[s]*dis[t]) : 0.f;
}

// ---------------- W conversion + stats/rn zeroing ----------------
// WT[layer][cout][k] f16, k = term*256 + cin
__global__ __launch_bounds__(256) void k_prepW(const float* __restrict__ Wa, const float* __restrict__ Wb,
                                               const float* __restrict__ Wc, u16* __restrict__ WT,
                                               float* __restrict__ stats /*[3][512]*/,
                                               float* __restrict__ rn) {
  int i = blockIdx.x*256 + threadIdx.x;
  if (i < 3*256*1536) {
    int layer = i / (256*1536);
    int rem = i - layer*(256*1536);
    int cout = rem / 1536, k = rem - cout*1536;
    int term = k >> 8, cin = k & 255;
    const float* W = (layer == 0) ? Wa : (layer == 1) ? Wb : Wc;
    WT[i] = f2h(W[(size_t)term*65536 + cin*256 + cout]);
  }
  if (i < 3*2*HD) stats[i] = 0.f;
  if (i < NODES) rn[i] = 0.f;
}

// ---------------- layer 1 fused: 5 sparse props (din=3) + [150x18]@[18x256] + BN stats ------------
__global__ __launch_bounds__(512) void k_l1(const float* __restrict__ x,
                                            const int* __restrict__ rowptr,
                                            const unsigned char* __restrict__ ccol,
                                            const float* __restrict__ cw,
                                            const float* __restrict__ W1,
                                            const float* __restrict__ b1,
                                            float* __restrict__ stats,
                                            u16* __restrict__ outc) {
  __shared__ float Ta[450], Tb[450];
  __shared__ float Tall_s[PJ*18];
  __shared__ float wl[18*256];
  __shared__ float cw_s[PJ*DEG];
  __shared__ u16  col_s[PJ*DEG];
  __shared__ int  rp_s[PJ+1];
  int j = blockIdx.x, tid = threadIdx.x;
  int jb = j*PJ, e0 = jb*DEG;
  for (int i = tid; i < 18*256; i += 512) wl[i] = W1[i];
  for (int i = tid; i < PJ*DEG; i += 512) { cw_s[i] = cw[e0+i]; col_s[i] = (u16)ccol[e0+i]; }
  for (int i = tid; i < PJ+1; i += 512) rp_s[i] = rowptr[jb+i] - e0;
  if (tid < 450) Ta[tid] = x[(size_t)jb*3 + tid];
  __syncthreads();
  int r = tid/3, c = tid - r*3;
  float* cur = Ta; float* oth = Tb;
  if (tid < 450) Tall_s[r*18 + c] = cur[tid];
  for (int t = 1; t < 6; ++t) {
    if (tid < 450) {
      int es = rp_s[r], ee = rp_s[r+1];
      float acc = 0.f;
      for (int e = es; e < ee; ++e) acc += cw_s[e]*cur[(int)col_s[e]*3 + c];
      float v = (t == 1) ? acc : 2.f*acc - oth[tid];
      oth[tid] = v;
      Tall_s[r*18 + t*3 + c] = v;
    }
    __syncthreads();
    float* tmp = cur; cur = oth; oth = tmp;
  }
  // GEMM: out[r][cc] = sum_i Tall_s[r][i]*wl[i][cc]; fused BN stats (bias b1)
  int cc = tid & 255, rhalf = tid >> 8;
  float bc = b1[cc];
  float s = 0.f, s2 = 0.f;
  int r0 = rhalf*75;
  for (int rr = r0; rr < r0 + 75; ++rr) {
    float acc = 0.f;
#pragma unroll
    for (int i = 0; i < 18; ++i) acc += Tall_s[rr*18 + i] * wl[i*256 + cc];
    outc[(size_t)(jb+rr)*HD + cc] = f2h(acc);
    float vb = acc + bc;
    s += vb; s2 += vb*vb;
  }
  atomicAdd(&stats[cc], s);
  atomicAdd(&stats[HD + cc], s2);
}

// ---------------- fused per-jet Chebyshev layer ----------------
// r14 structure; Ls now built IN-BLOCK from CSR (no global Lg). Stage covers rows <150 only;
// Tn rows 150..159 zeroed once (Ls cols 150-159 are exact 0 -> finite garbage masked, NaN not).
template<int OMODE>
__global__ __launch_bounds__(1024, 4) void k_cheb(const u16* __restrict__ IN,
                                                  const u16* __restrict__ WTu,
                                                  const int* __restrict__ rowptr,
                                                  const unsigned char* __restrict__ ccol,
                                                  const float* __restrict__ cw,
                                                  const float* __restrict__ statsPrev,
                                                  const float* __restrict__ gP,
                                                  const float* __restrict__ beP,
                                                  const float* __restrict__ bP,
                                                  const float* __restrict__ bCur,
                                                  float* __restrict__ statsCur,
                                                  float* __restrict__ rn,
                                                  u16* __restrict__ OUTp) {
  __shared__ u16 Ls[160*LSTR];         // 61.4 KB
  __shared__ u16 Tn[2][160*TNS];       // 41.0 KB
  __shared__ u16 Tt[2][64*LSTR];       // 49.2 KB
  __shared__ float bnA[HD], bnB[HD];   // 2 KB   -> 153.6 KB total
  int j = blockIdx.x, tid = threadIdx.x;
  int jb = j*PJ;
  int lane = tid & 63, wid = tid >> 6;
  int wm = wid >> 3, wn = wid & 7;          // 2(M) x 8(N)
  int lr = lane & 15, lg = lane >> 4;
  int ph = wn >> 2, cs = wn & 3;            // prop: half + 16-ch slice
  int cown = cs*16 + lr;
  // ---- hoisted thread-invariant swizzle offsets (u16 units) ----
  int key   = lr & 7;
  int segA0 = ((lg    ) ^ key) * 8;
  int segA1 = ((lg + 4) ^ key) * 8;
  int pOff[5] = { segA0, segA1, 64 + segA0, 64 + segA1, 128 + segA0 };
  int ep0 = ((cown >> 3) ^ ((lg & 1)*4 + 0)) * 8 + (cown & 7);
  int ep1 = ((cown >> 3) ^ ((lg & 1)*4 + 1)) * 8 + (cown & 7);
  int ep2 = ((cown >> 3) ^ ((lg & 1)*4 + 2)) * 8 + (cown & 7);
  int ep3 = ((cown >> 3) ^ ((lg & 1)*4 + 3)) * 8 + (cown & 7);
  int cownL = cown * LSTR;
  const f16* WT = (const f16*)WTu;
  const f16* wtb = WT + (size_t)(wn*32 + lr)*1536 + lg*8;

  // BN tables
  if (tid < HD) {
    const float invN = 1.f/(float)NODES;
    float m = statsPrev[tid]*invN;
    float var = statsPrev[HD+tid]*invN - m*m;
    float A = rsqrtf(var + 1e-5f) * gP[tid];
    bnA[tid] = A;
    bnB[tid] = (bP[tid] - m)*A + beP[tid];
  }
  // zero Ls + Tn pad rows (150..159, both halves)
  {
    u16x8 z = {0,0,0,0,0,0,0,0};
    for (int i = tid; i < 3840; i += 1024) *(u16x8*)&Ls[i*8] = z;
    for (int i = tid; i < 160; i += 1024) {         // 10 rows x 8 segs x 2 halves
      int h = i >= 80 ? 1 : 0;
      int rem = i - h*80;
      int row = 150 + (rem >> 3), seg = rem & 7;
      *(u16x8*)&Tn[h][row*TNS + seg*8] = z;
    }
  }
  __syncthreads();
  // build dense 2*Lhat in LDS from CSR (thread r owns row r; swizzled element addressing)
  if (tid < PJ) {
    int es = rowptr[jb + tid], ee = rowptr[jb + tid + 1];
    for (int e = es; e < ee; ++e) {
      int c = (int)ccol[e];
      int a = tid*LSTR + swz(c >> 3, tid)*8 + (c & 7);
      Ls[a] = f2h(h2f(Ls[a]) + 2.f*cw[e]);
    }
  }
  f32x4 acc[5][2];
#pragma unroll
  for (int a = 0; a < 5; ++a)
#pragma unroll
    for (int b = 0; b < 2; ++b) acc[a][b] = (f32x4)0.f;

  u16x4 tc0, tc1, tc2, tc3, tc4, tp0, tp1, tp2, tp3, tp4;

  for (int qp = 0; qp < 2; ++qp) {
    __syncthreads();   // prior-pair reads done; Ls build / bn staged at qp=0
    // stage T0 = lrelu(BN(IN)) for quarters (qp*2, qp*2+1); rows < 150 only
    for (int i = tid; i < 2400; i += 1024) {
      int h = (i >= 1200) ? 1 : 0;
      int rem = i - h*1200;
      int row = rem >> 3, seg = rem & 7;
      int c0 = (qp*2+h)*64 + seg*8;
      u16x8 v = *(const u16x8*)&IN[(size_t)(jb+row)*HD + c0];
      u16x8 o;
#pragma unroll
      for (int u = 0; u < 8; ++u) {
        float f = h2f(v[u])*bnA[c0+u] + bnB[c0+u];
        o[u] = f2h((f > 0.f) ? f : 0.01f*f);
      }
      *(u16x8*)&Tn[h][row*TNS + (seg ^ (row & 7))*8] = o;
    }
    __syncthreads();
    // build Ttr (swizzled both sides; rows 150-159 of Tn are finite -> OK)
    for (int i = tid; i < 2560; i += 1024) {
      int h = (i >= 1280) ? 1 : 0;
      int rem = i - h*1280;
      int c = rem & 63, m = rem >> 6;
      u16x8 v;
#pragma unroll
      for (int u = 0; u < 8; ++u) {
        int r = m*8 + u;
        v[u] = Tn[h][r*TNS + ((c >> 3) ^ (r & 7))*8 + (c & 7)];
      }
      *(u16x8*)&Tt[h][c*LSTR + swz(m, c)*8] = v;
    }
    // own-slot T0 into named registers
#define TINIT(MF, TC, TP) { int r0 = wm*80 + MF*16 + lg*4; u16x4 t; \
    t[0] = Tn[ph][(r0+0)*TNS + ep0]; t[1] = Tn[ph][(r0+1)*TNS + ep1]; \
    t[2] = Tn[ph][(r0+2)*TNS + ep2]; t[3] = Tn[ph][(r0+3)*TNS + ep3]; \
    TC = t; TP = t; }
    TINIT(0, tc0, tp0) TINIT(1, tc1, tp1) TINIT(2, tc2, tp2) TINIT(3, tc3, tp3) TINIT(4, tc4, tp4)
#undef TINIT
    __syncthreads();
#pragma unroll 1
    for (int t = 0; t < 6; ++t) {
#pragma unroll
      for (int h = 0; h < 2; ++h) {
        int kbase = t*256 + (qp*2+h)*64;
#pragma unroll
        for (int ks = 0; ks < 64; ks += 32) {
          int segA = (ks == 0) ? segA0 : segA1;
          f16x8 a[5], bv[2];
#pragma unroll
          for (int nf = 0; nf < 2; ++nf)
            bv[nf] = *(const f16x8*)&wtb[nf*24576 + kbase + ks];
#pragma unroll
          for (int mf = 0; mf < 5; ++mf) {
            int row = wm*80 + mf*16 + lr;
            a[mf] = *(const f16x8*)&Tn[h][row*TNS + segA];
          }
#pragma unroll
          for (int nf = 0; nf < 2; ++nf)
#pragma unroll
            for (int mf = 0; mf < 5; ++mf)
              acc[mf][nf] = __builtin_amdgcn_mfma_f32_16x16x32_f16(a[mf], bv[nf], acc[mf][nf], 0, 0, 0);
        }
      }
      if (t < 5) {
        f32x4 pacc[5];
#pragma unroll
        for (int mf = 0; mf < 5; ++mf) pacc[mf] = (f32x4)0.f;
#pragma unroll
        for (int ks = 0; ks < 5; ++ks) {
          f16x8 b = *(const f16x8*)&Tt[ph][cownL + pOff[ks]];
#pragma unroll
          for (int mf = 0; mf < 5; ++mf) {
            int row = wm*80 + mf*16 + lr;
            f16x8 a = *(const f16x8*)&Ls[row*LSTR + pOff[ks]];
            pacc[mf] = __builtin_amdgcn_mfma_f32_16x16x32_f16(a, b, pacc[mf], 0, 0, 0);
          }
        }
        __syncthreads();
#define TEPI(MF, TC, TP) { int r0 = wm*80 + MF*16 + lg*4; u16x4 o; \
        { float v0_ = (t == 0) ? 0.5f*pacc[MF][0] : pacc[MF][0] - h2f(TP[0]); o[0] = f2h(v0_); } \
        { float v1_ = (t == 0) ? 0.5f*pacc[MF][1] : pacc[MF][1] - h2f(TP[1]); o[1] = f2h(v1_); } \
        { float v2_ = (t == 0) ? 0.5f*pacc[MF][2] : pacc[MF][2] - h2f(TP[2]); o[2] = f2h(v2_); } \
        { float v3_ = (t == 0) ? 0.5f*pacc[MF][3] : pacc[MF][3] - h2f(TP[3]); o[3] = f2h(v3_); } \
        Tn[ph][(r0+0)*TNS + ep0] = o[0]; Tn[ph][(r0+1)*TNS + ep1] = o[1]; \
        Tn[ph][(r0+2)*TNS + ep2] = o[2]; Tn[ph][(r0+3)*TNS + ep3] = o[3]; \
        int sgT = wm*10 + MF*2 + (lg >> 1); \
        int segT = (sgT & ~7) | ((sgT & 7) ^ key); \
        *(u16x4*)&Tt[ph][cownL + segT*8 + (lg & 1)*4] = o; \
        TP = TC; TC = o; }
        TEPI(0, tc0, tp0) TEPI(1, tc1, tp1) TEPI(2, tc2, tp2) TEPI(3, tc3, tp3) TEPI(4, tc4, tp4)
#undef TEPI
        __syncthreads();
      }
    }
  }
  // ---- OUT epilogue + fused stats / rowsumsq ----
  if (OMODE == 0) {
#pragma unroll
    for (int nf = 0; nf < 2; ++nf) {
      int col = wn*32 + nf*16 + lr;
      float bc = bCur[col];
      float s = 0.f, s2 = 0.f;
#pragma unroll
      for (int mf = 0; mf < 5; ++mf) {
        int row = wm*80 + mf*16 + lg*4;
#pragma unroll
        for (int e = 0; e < 4; ++e) {
          int r = row + e;
          if (r < PJ) {
            float v = acc[mf][nf][e];
            OUTp[(size_t)(jb+r)*HD + col] = f2h(v);
            float vb = v + bc;
            s += vb; s2 += vb*vb;
          }
        }
      }
      s  += __shfl_xor(s, 16, 64);  s  += __shfl_xor(s, 32, 64);
      s2 += __shfl_xor(s2, 16, 64); s2 += __shfl_xor(s2, 32, 64);
      if (lg == 0) {
        atomicAdd(&statsCur[col], s);
        atomicAdd(&statsCur[HD + col], s2);
      }
    }
  } else {
    float bc[2];
#pragma unroll
    for (int nf = 0; nf < 2; ++nf) bc[nf] = bCur[wn*32 + nf*16 + lr];
#pragma unroll
    for (int mf = 0; mf < 5; ++mf) {
      int row = wm*80 + mf*16 + lg*4;
#pragma unroll
      for (int e = 0; e < 4; ++e) {
        int r = row + e;
        float srow = 0.f;
        if (r < PJ) {
#pragma unroll
          for (int nf = 0; nf < 2; ++nf) {
            int col = wn*32 + nf*16 + lr;
            float v = acc[mf][nf][e];
            OUTp[(size_t)(jb+r)*HD + col] = f2h(v);
            float vb = v + bc[nf];
            srow += vb*vb;
          }
        }
        srow += __shfl_xor(srow, 1, 64);
        srow += __shfl_xor(srow, 2, 64);
        srow += __shfl_xor(srow, 4, 64);
        srow += __shfl_xor(srow, 8, 64);
        if (lr == 0 && r < PJ) atomicAdd(&rn[jb + r], srow);
      }
    }
  }
}

// ---------------- distance softmax pooling, fused row-normalize ----------------

__global__ __launch_bounds__(256) void k_pool(const u16* __restrict__ h, const float* __restrict__ rn,
                                              const float* __restrict__ bias, const float* __restrict__ x,
                                              const float* __restrict__ centers, const float* __restrict__ log_temp,
                                              float* __restrict__ out) {
  __shared__ float a_s[PJ][NCL];
  __shared__ float colsum[NCL];
  __shared__ float inv_s[PJ];
  int j = blockIdx.x;
  int tid = threadIdx.x;
  float T = expf(fminf(fmaxf(log_temp[0], -2.f), 3.f));
  if (tid < PJ) {
    int g = j*PJ + tid;
    inv_s[tid] = 1.f / fmaxf(sqrtf(rn[g]), 1e-12f);
    float eta = x[(size_t)g*3], phi = x[(size_t)g*3 + 1];
    float d[NCL];
    float dmin = 1e30f;
#pragma unroll
    for (int k = 0; k < NCL; ++k) {
      float dx = eta - centers[2*k], dy = phi - centers[2*k+1];
      d[k] = dx*dx + dy*dy;
      dmin = fminf(dmin, d[k]);
    }
    float s = 0.f, ek[NCL];
#pragma unroll
    for (int k = 0; k < NCL; ++k) { ek[k] = expf(-T*(d[k]-dmin)); s += ek[k]; }
    float invs = 1.f/s;
#pragma unroll
    for (int k = 0; k < NCL; ++k) a_s[tid][k] = ek[k]*invs;
  }
  __syncthreads();
  if (tid < NCL) {
    float s = 0.f;
    for (int n = 0; n < PJ; ++n) s += a_s[n][tid];
    colsum[tid] = s;
  }
  __syncthreads();
  int c = tid;
  float bc = bias[c];
  float acc[NCL] = {};
  for (int n = 0; n < PJ; ++n) {
    float hv = (h2f(h[(size_t)(j*PJ + n)*HD + c]) + bc) * inv_s[n];
#pragma unroll
    for (int k = 0; k < NCL; ++k) acc[k] += a_s[n][k]*hv;
  }
#pragma unroll
  for (int k = 0; k < NCL; ++k)
    out[(size_t)j*(NCL*HD) + k*HD + c] = acc[k] / (colsum[k] + 1e-8f);
}

// ---------------- host ----------------

extern "C" void kernel_launch(void* const* d_in, const int* in_sizes, int n_in,
                              void* d_out, int out_size, void* d_ws, size_t ws_size,
                              hipStream_t stream) {
  (void)in_sizes; (void)n_in; (void)out_size;
  const float* x   = (const float*)d_in[0];
  const int*   ei  = (const int*)d_in[1];
  const int*   srcA = ei;
  const int*   tgtA = ei + NEDGE;
  const float* W1  = (const float*)d_in[3];
  const float* b1  = (const float*)d_in[4];
  const float* W2  = (const float*)d_in[5];
  const float* b2  = (const float*)d_in[6];
  const float* W3  = (const float*)d_in[7];
  const float* b3  = (const float*)d_in[8];
  const float* W4  = (const float*)d_in[9];
  const float* b4  = (const float*)d_in[10];
  const float* g1  = (const float*)d_in[11];
  const float* be1 = (const float*)d_in[12];
  const float* g2  = (const float*)d_in[13];
  const float* be2 = (const float*)d_in[14];
  const float* g3  = (const float*)d_in[15];
  const float* be3 = (const float*)d_in[16];
  const float* centers  = (const float*)d_in[17];
  const float* log_temp = (const float*)d_in[18];
  float* out = (float*)d_out;

  auto rb = [](size_t b) { return (b + 255) & ~(size_t)255; };
  size_t need = 2*rb((size_t)NODES*HD*2)            // OUTA, OUTB
              + rb((size_t)3*256*1536*2)            // Wcat
              + 3*rb((size_t)NODES*4)               // dis, counts, cursor
              + rb((size_t)(NODES+1)*4)             // rowptr
              + rb((size_t)NEDGE)                   // ccol
              + rb((size_t)NEDGE*4)                 // cw
              + rb((size_t)3*2*HD*4)                // stats x3
              + rb((size_t)NODES*4);                // rn
  fprintf(stderr, "[kernel_launch] ws_size=%zu need=%zu\n", ws_size, need);
  if (d_ws == nullptr || ws_size < need) {
    float code = 1.0e6f + (float)(ws_size >> 20);
    k_diag<<<1, 1, 0, stream>>>(out, code);
    return;
  }

  char* wp = (char*)d_ws;
  auto alloc = [&](size_t b) -> void* {
    void* p = (void*)wp;
    wp += (b + 255) & ~(size_t)255;
    return p;
  };
  u16*   OUTA = (u16*)alloc((size_t)NODES*HD*2);
  u16*   OUTB = (u16*)alloc((size_t)NODES*HD*2);
  u16*   Wcat = (u16*)alloc((size_t)3*256*1536*2);
  float* dis  = (float*)alloc((size_t)NODES*4);
  int*   counts = (int*)alloc((size_t)NODES*4);
  int*   cursor = (int*)alloc((size_t)NODES*4);
  int*   rowptr = (int*)alloc((size_t)(NODES+1)*4);
  unsigned char* ccol = (unsigned char*)alloc((size_t)NEDGE);
  float* cw     = (float*)alloc((size_t)NEDGE*4);
  float* stats  = (float*)alloc((size_t)3*2*HD*4);   // [3][512]
  float* rn     = (float*)alloc((size_t)NODES*4);
  float* s0 = stats, *s1 = stats + 512, *s2 = stats + 1024;

  // graph preprocessing
  hipMemsetAsync(counts, 0, (size_t)NODES*4, stream);
  k_discounts<<<(NEDGE+255)/256, 256, 0, stream>>>(tgtA, counts, dis);
  k_scan<<<(NJETS+255)/256, 256, 0, stream>>>(counts, rowptr, cursor);
  k_fill<<<(NEDGE+255)/256, 256, 0, stream>>>(srcA, tgtA, dis, cursor, ccol, cw);

  // W conversion + all stats/rn zeroing (independent of layer 1)
  k_prepW<<<(3*256*1536+255)/256, 256, 0, stream>>>(W2, W3, W4, Wcat, stats, rn);

  // ---- layer 1 fused (props + GEMM + stats) ----
  k_l1<<<NJETS, 512, 0, stream>>>(x, rowptr, ccol, cw, W1, b1, s0, OUTA);

  // ---- layers 2..4: fused all-MFMA Cheb, BN-on-stage, in-block L build ----
  k_cheb<0><<<NJETS, 1024, 0, stream>>>(OUTA, Wcat,            rowptr, ccol, cw, s0, g1, be1, b1, b2, s1, rn, OUTB);
  k_cheb<0><<<NJETS, 1024, 0, stream>>>(OUTB, Wcat + 393216,   rowptr, ccol, cw, s1, g2, be2, b2, b3, s2, rn, OUTA);
  k_cheb<1><<<NJETS, 1024, 0, stream>>>(OUTA, Wcat + 2*393216, rowptr, ccol, cw, s2, g3, be3, b3, b4, s2, rn, OUTB);

  // ---- pooling (fused rownorm) ----
  k_pool<<<NJETS, 256, 0, stream>>>(OUTB, rn, b4, x, centers, log_temp, out);
}